// Round 1
// baseline (410.466 us; speedup 1.0000x reference)
//
#include <hip/hip_runtime.h>
#include <hip/hip_bf16.h>
#include <cstdint>

typedef __bf16 bf16x8 __attribute__((ext_vector_type(8)));
typedef float  f32x4  __attribute__((ext_vector_type(4)));

__device__ __forceinline__ unsigned short f2bf(float f) {
  __hip_bfloat16 h = __float2bfloat16(f);
  return __builtin_bit_cast(unsigned short, h);
}
__device__ __forceinline__ float bf2f(unsigned short u) {
  return __builtin_bit_cast(float, (unsigned)u << 16);
}

#define GL2LDS16(gp, lp)                                                      \
  __builtin_amdgcn_global_load_lds(                                           \
      (const __attribute__((address_space(1))) unsigned int*)(gp),            \
      (__attribute__((address_space(3))) unsigned int*)(lp), 16, 0, 0)

// m97-style GEMM: C[m][n] = sum_k A[m][k] * B[n][k]  (B given transposed)
// 128x128 tile, BK=32, 4 waves (each 64x64 = 4x4 fragments of 16x16x32 bf16).
// Epilogue modes:
//  0: bf16 out, col bias, elu+1      (Qp)
//  1: bf16 out, row bias, elu+1      (KpT)
//  2: bf16 out, row bias, no act     (VT)
//  3: bf16 out, no bias              (KVt)
//  4: f32 out, divide by norm[row]   (numerator -> final output)
template <int MODE>
__global__ __launch_bounds__(256) void gemm_bt(
    const unsigned short* __restrict__ A, long long lda, long long aOffZ,
    const unsigned short* __restrict__ B, long long ldb, long long bOffZ,
    void* __restrict__ C, long long ldc, long long cOffZ,
    const float* __restrict__ bias, const float* __restrict__ norm,
    long long normOffZ, int K) {
  const int t = threadIdx.x;
  const int wave = t >> 6, lane = t & 63;
  const int wr = wave >> 1, wc = wave & 1;
  const int fr = lane & 15, fq = lane >> 4;
  const long long z = blockIdx.z;
  const unsigned short* Az = A + z * aOffZ;
  const unsigned short* Bz = B + z * bOffZ;
  const int m0 = blockIdx.y * 128, n0 = blockIdx.x * 128;

  __shared__ __attribute__((aligned(16))) unsigned short lsA[128 * 32];
  __shared__ __attribute__((aligned(16))) unsigned short lsB[128 * 32];

  // staging: 256 threads x 16B = 4KB per inst; tile = 8KB -> 2 insts/operand.
  // linear slot off8 = i*256 + t maps to (row = off8>>2, kchunk = off8&3),
  // LDS byte = off8*16 (linear in lane order as global_load_lds requires).
  const int srow = t >> 2, sch = t & 3;
  const unsigned short* gA0 = Az + (long long)(m0 + srow) * lda + sch * 8;
  const unsigned short* gA1 = Az + (long long)(m0 + 64 + srow) * lda + sch * 8;
  const unsigned short* gB0 = Bz + (long long)(n0 + srow) * ldb + sch * 8;
  const unsigned short* gB1 = Bz + (long long)(n0 + 64 + srow) * ldb + sch * 8;
  unsigned short* lA0 = &lsA[wave * 512];          // wave-uniform bases
  unsigned short* lA1 = &lsA[2048 + wave * 512];
  unsigned short* lB0 = &lsB[wave * 512];
  unsigned short* lB1 = &lsB[2048 + wave * 512];

  int aoff[4], boff[4];
#pragma unroll
  for (int i = 0; i < 4; ++i) {
    aoff[i] = (wr * 64 + i * 16 + fr) * 32 + fq * 8;
    boff[i] = (wc * 64 + i * 16 + fr) * 32 + fq * 8;
  }

  f32x4 acc[4][4];
#pragma unroll
  for (int i = 0; i < 4; ++i)
#pragma unroll
    for (int j = 0; j < 4; ++j) acc[i][j] = (f32x4){0.f, 0.f, 0.f, 0.f};

  for (int kt = 0; kt < K; kt += 32) {
    GL2LDS16(gA0 + kt, lA0);
    GL2LDS16(gA1 + kt, lA1);
    GL2LDS16(gB0 + kt, lB0);
    GL2LDS16(gB1 + kt, lB1);
    __syncthreads();  // drains vmcnt before barrier (compiler-enforced)
    bf16x8 av[4], bv[4];
#pragma unroll
    for (int i = 0; i < 4; ++i) {
      av[i] = *reinterpret_cast<const bf16x8*>(&lsA[aoff[i]]);
      bv[i] = *reinterpret_cast<const bf16x8*>(&lsB[boff[i]]);
    }
#pragma unroll
    for (int mi = 0; mi < 4; ++mi)
#pragma unroll
      for (int ni = 0; ni < 4; ++ni)
        acc[mi][ni] = __builtin_amdgcn_mfma_f32_16x16x32_bf16(
            av[mi], bv[ni], acc[mi][ni], 0, 0, 0);
    __syncthreads();
  }

  // epilogue. C/D layout: col = lane&15, row = (lane>>4)*4 + j  [m89-verified]
  const float* nrmz = (MODE == 4) ? (norm + z * normOffZ) : nullptr;
  float* Cf = (float*)C + z * cOffZ;
  unsigned short* Cu = (unsigned short*)C + z * cOffZ;

#pragma unroll
  for (int mi = 0; mi < 4; ++mi) {
    const int rbase = m0 + wr * 64 + mi * 16 + fq * 4;
    float rb[4], nv[4];
#pragma unroll
    for (int j = 0; j < 4; ++j) {
      if (MODE == 1 || MODE == 2) rb[j] = bias[rbase + j];
      if (MODE == 4) nv[j] = nrmz[rbase + j];
    }
#pragma unroll
    for (int ni = 0; ni < 4; ++ni) {
      const int c = n0 + wc * 64 + ni * 16 + fr;
      float cb = 0.f;
      if (MODE == 0) cb = bias[c];
#pragma unroll
      for (int j = 0; j < 4; ++j) {
        float v = acc[mi][ni][j];
        if (MODE == 0) v += cb;
        if (MODE == 1 || MODE == 2) v += rb[j];
        if (MODE == 0 || MODE == 1) v = (v > 0.f) ? v + 1.f : __expf(v);
        const long long ci = (long long)(rbase + j) * ldc + c;
        if (MODE == 4)
          Cf[ci] = v / nv[j];
        else
          Cu[ci] = f2bf(v);
      }
    }
  }
}

// W [1024(in)][1024(out)] f32  ->  WT [1024(out)][1024(in)] bf16
__global__ __launch_bounds__(256) void transpose_w(
    const float* __restrict__ W, unsigned short* __restrict__ WT) {
  __shared__ float tile[32][33];
  const int tx = threadIdx.x & 31, ty = threadIdx.x >> 5;
  const int i0 = blockIdx.y * 32, o0 = blockIdx.x * 32;
#pragma unroll
  for (int s = 0; s < 32; s += 8)
    tile[ty + s][tx] = W[(long long)(i0 + ty + s) * 1024 + o0 + tx];
  __syncthreads();
#pragma unroll
  for (int s = 0; s < 32; s += 8)
    WT[(long long)(o0 + ty + s) * 1024 + i0 + tx] = f2bf(tile[tx][ty + s]);
}

__global__ __launch_bounds__(256) void convert_x(
    const float4* __restrict__ in, uint2* __restrict__ out, int n4) {
  const int stride = gridDim.x * blockDim.x;
  for (int i = blockIdx.x * blockDim.x + threadIdx.x; i < n4; i += stride) {
    float4 v = in[i];
    uint2 o;
    o.x = (unsigned)f2bf(v.x) | ((unsigned)f2bf(v.y) << 16);
    o.y = (unsigned)f2bf(v.z) | ((unsigned)f2bf(v.w) << 16);
    out[i] = o;
  }
}

// K_sum[b][d] = sum_n KpT[d][b*4096 + n]   (one wave per (b,d))
__global__ __launch_bounds__(256) void ksum_kernel(
    const unsigned short* __restrict__ KpT, float* __restrict__ Ksum) {
  const int gw = (blockIdx.x * 256 + threadIdx.x) >> 6;  // 0..4095
  const int lane = threadIdx.x & 63;
  const int d = gw >> 2, b = gw & 3;
  const unsigned short* p = KpT + (long long)d * 16384 + b * 4096;
  float s = 0.f;
  for (int i = lane; i < 4096; i += 64) s += bf2f(p[i]);
#pragma unroll
  for (int o = 32; o > 0; o >>= 1) s += __shfl_down(s, o, 64);
  if (lane == 0) Ksum[b * 1024 + d] = s;
}

// nrm[m] = eps + sum_d Qp[m][d] * Ksum[b][d]   (one wave per row m)
__global__ __launch_bounds__(256) void norm_kernel(
    const unsigned short* __restrict__ Qp, const float* __restrict__ Ksum,
    float* __restrict__ nrm) {
  const int gw = (blockIdx.x * 256 + threadIdx.x) >> 6;  // 0..16383
  const int lane = threadIdx.x & 63;
  const int b = gw >> 12;
  const unsigned short* q = Qp + (long long)gw * 1024;
  const float* ks = Ksum + b * 1024;
  float s = 0.f;
  for (int i = lane; i < 1024; i += 64) s += bf2f(q[i]) * ks[i];
#pragma unroll
  for (int o = 32; o > 0; o >>= 1) s += __shfl_down(s, o, 64);
  if (lane == 0) nrm[gw] = s + 1e-6f;
}

extern "C" void kernel_launch(void* const* d_in, const int* in_sizes, int n_in,
                              void* d_out, int out_size, void* d_ws,
                              size_t ws_size, hipStream_t stream) {
  const float* x  = (const float*)d_in[0];
  const float* Wq = (const float*)d_in[1];
  const float* bq = (const float*)d_in[2];
  const float* Wk = (const float*)d_in[3];
  const float* bk = (const float*)d_in[4];
  const float* Wv = (const float*)d_in[5];
  const float* bv = (const float*)d_in[6];
  float* out = (float*)d_out;

  const size_t MN = 16384ull * 1024ull;  // B*N*D elements
  char* w = (char*)d_ws;
  unsigned short* xb  = (unsigned short*)w;  w += MN * 2;                 // x bf16 [16384][1024]
  unsigned short* WT  = (unsigned short*)w;  w += 3ull * 1024 * 1024 * 2; // Wq^T|Wk^T|Wv^T bf16
  unsigned short* Qp  = (unsigned short*)w;  w += MN * 2;                 // [16384][1024]
  unsigned short* KpT = (unsigned short*)w;  w += MN * 2;                 // [1024][16384]
  unsigned short* VT  = (unsigned short*)w;  w += MN * 2;                 // [1024][16384]
  unsigned short* KVt = (unsigned short*)w;  w += 4ull * 1024 * 1024 * 2; // [4][1024(e)][1024(d)]
  float* Ksum = (float*)w;  w += 4ull * 1024 * 4;                         // [4][1024]
  float* nrm  = (float*)w;  w += 16384ull * 4;                            // [16384]

  transpose_w<<<dim3(32, 32), 256, 0, stream>>>(Wq, WT);
  transpose_w<<<dim3(32, 32), 256, 0, stream>>>(Wk, WT + 1024 * 1024);
  transpose_w<<<dim3(32, 32), 256, 0, stream>>>(Wv, WT + 2 * 1024 * 1024);
  convert_x<<<2048, 256, 0, stream>>>((const float4*)x, (uint2*)xb,
                                      (int)(MN / 4));

  // Qp = elu(x @ Wq + bq)+1 : A=xb[16384][1024], Bt=WqT[1024][1024]
  gemm_bt<0><<<dim3(8, 128, 1), 256, 0, stream>>>(
      xb, 1024, 0, WT, 1024, 0, Qp, 1024, 0, bq, nullptr, 0, 1024);
  // KpT = (elu(x @ Wk + bk)+1)^T : A=WkT[1024][1024], Bt=xb[16384][1024]
  gemm_bt<1><<<dim3(128, 8, 1), 256, 0, stream>>>(
      WT + 1024 * 1024, 1024, 0, xb, 1024, 0, KpT, 16384, 0, bk, nullptr, 0,
      1024);
  // VT = (x @ Wv + bv)^T
  gemm_bt<2><<<dim3(128, 8, 1), 256, 0, stream>>>(
      WT + 2 * 1024 * 1024, 1024, 0, xb, 1024, 0, VT, 16384, 0, bv, nullptr, 0,
      1024);
  ksum_kernel<<<1024, 256, 0, stream>>>(KpT, Ksum);
  // KVt[b][e][d] = sum_n VT[e][bn] * KpT[d][bn]  (K=4096 per batch)
  gemm_bt<3><<<dim3(8, 8, 4), 256, 0, stream>>>(
      VT, 16384, 4096, KpT, 16384, 4096, KVt, 1024, 1024 * 1024, nullptr,
      nullptr, 0, 4096);
  norm_kernel<<<4096, 256, 0, stream>>>(Qp, Ksum, nrm);
  // out[b][n][e] = (sum_d Qp[bn][d] * KVt[b][e][d]) / nrm[bn]
  gemm_bt<4><<<dim3(8, 32, 4), 256, 0, stream>>>(
      Qp, 1024, 4096ll * 1024, KVt, 1024, 1024 * 1024, out, 1024,
      4096ll * 1024, nullptr, nrm, 4096, 1024);
}

// Round 2
// 335.373 us; speedup vs baseline: 1.2239x; 1.2239x over previous
//
#include <hip/hip_runtime.h>
#include <hip/hip_bf16.h>
#include <cstdint>

typedef __bf16 bf16x8 __attribute__((ext_vector_type(8)));
typedef float  f32x4  __attribute__((ext_vector_type(4)));

__device__ __forceinline__ unsigned short f2bf(float f) {
  __hip_bfloat16 h = __float2bfloat16(f);
  return __builtin_bit_cast(unsigned short, h);
}
__device__ __forceinline__ float bf2f(unsigned short u) {
  return __builtin_bit_cast(float, (unsigned)u << 16);
}

#define GL2LDS16(gp, lp)                                                      \
  __builtin_amdgcn_global_load_lds(                                           \
      (const __attribute__((address_space(1))) unsigned int*)(gp),            \
      (__attribute__((address_space(3))) unsigned int*)(lp), 16, 0, 0)

#define SBAR                                                                  \
  {                                                                           \
    __builtin_amdgcn_s_barrier();                                             \
    __builtin_amdgcn_sched_barrier(0);                                        \
  }
#define WAITV(n)                                                              \
  {                                                                           \
    asm volatile("s_waitcnt vmcnt(" #n ")" ::: "memory");                     \
    __builtin_amdgcn_sched_barrier(0);                                        \
  }
#define WAITL0                                                                \
  {                                                                           \
    asm volatile("s_waitcnt lgkmcnt(0)" ::: "memory");                        \
    __builtin_amdgcn_sched_barrier(0);                                        \
  }

// 256x256-tile GEMM, C[m][n] = sum_k A[m][k]*B[n][k] (B transposed layout).
// BK=32, 8 waves (2Mx4N), per-wave 128x64 output = acc[8][4] of 16x16 frags.
// 4-deep LDS K-tile ring (4 x 32KB = 128KB), lookahead-2 counted-vmcnt
// pipeline: per K-tile {P0: 8 ds_read + stage(t+2) + 16 MFMA | P1: 4 ds_read
// + 16 MFMA + vmcnt(4)}. Raw s_barrier; never vmcnt(0) in the main loop.
// LDS swizzle: phys = logical ^ (((logical>>7)&3)<<4)  (16B slot x row bits),
// applied on BOTH the pre-swizzled global source and the ds_read address.
// Epilogue modes: 0 Qp (col bias+elu+1), 1 KpT (row bias+elu+1),
// 2 VT (row bias), 3 KVt (plain bf16), 4 numerator (f32, /norm[row]).
template <int MODE>
__global__ __launch_bounds__(512, 2) void gemm256(
    const unsigned short* __restrict__ A, long long lda, long long aOffZ,
    const unsigned short* __restrict__ B, long long ldb, long long bOffZ,
    void* __restrict__ C, long long ldc, long long cOffZ,
    const float* __restrict__ bias, const float* __restrict__ norm,
    long long normOffZ, int K) {
  __shared__ __attribute__((aligned(16))) char lds[4 * 32768];
  const int t = threadIdx.x;
  const int wave = t >> 6, lane = t & 63;
  const int wm = wave >> 2, wn = wave & 3;
  const int fr = lane & 15, fq = lane >> 4;

  // bijective XCD swizzle on flat block id (grids here are %8==0)
  const int gx = gridDim.x, gy = gridDim.y;
  int flat = blockIdx.y * gx + blockIdx.x;
  const int total = gx * gy;
  if ((total & 7) == 0) flat = (flat & 7) * (total >> 3) + (flat >> 3);
  const int bx = flat % gx, by = flat / gx;
  const int m0 = by * 256, n0 = bx * 256;

  const long long z = blockIdx.z;
  const unsigned short* Az = A + z * aOffZ;
  const unsigned short* Bz = B + z * bOffZ;

  // staging sources: thread t's 16B lands at linear LDS byte d=c*8192+t*16;
  // content there must be logical byte l = d ^ (((d>>7)&3)<<4).
  const unsigned short* gA[2];
  const unsigned short* gB[2];
#pragma unroll
  for (int c = 0; c < 2; ++c) {
    int d = c * 8192 + t * 16;
    int l = d ^ (((d >> 7) & 3) << 4);
    int row = l >> 6, kel = (l & 63) >> 1;
    gA[c] = Az + (long long)(m0 + row) * lda + kel;
    gB[c] = Bz + (long long)(n0 + row) * ldb + kel;
  }

  // fragment read offsets (physical, swizzle folded in; lane-constant XOR)
  const int slotx = (fr >> 1) & 3;
  const int abase = wm * 8192 + fr * 64 + ((fq ^ slotx) << 4);
  const int bbase = 16384 + wn * 4096 + fr * 64 + ((fq ^ slotx) << 4);

  f32x4 acc[8][4];
#pragma unroll
  for (int i = 0; i < 8; ++i)
#pragma unroll
    for (int j = 0; j < 4; ++j) acc[i][j] = (f32x4){0.f, 0.f, 0.f, 0.f};

  const int NT = K >> 5;

  auto stage = [&](int tile) {
    const int k0 = tile << 5;
    char* bufp = lds + (tile & 3) * 32768;
#pragma unroll
    for (int c = 0; c < 2; ++c)
      GL2LDS16(gA[c] + k0, bufp + c * 8192 + wave * 1024);
#pragma unroll
    for (int c = 0; c < 2; ++c)
      GL2LDS16(gB[c] + k0, bufp + 16384 + c * 8192 + wave * 1024);
  };

  stage(0);
  stage(1);
  WAITV(4);  // tile 0 landed (tile 1's 4 loads may be outstanding)
  SBAR;

  bf16x8 av[4], bv[4];
  for (int tt = 0; tt + 2 < NT; ++tt) {
    const char* bufp = lds + (tt & 3) * 32768;
    // ---- phase 0: frags (A mi0-3, B ni0-3) + prefetch tile tt+2
#pragma unroll
    for (int i = 0; i < 4; ++i) {
      av[i] = *(const bf16x8*)(bufp + abase + i * 1024);
      bv[i] = *(const bf16x8*)(bufp + bbase + i * 1024);
    }
    stage(tt + 2);
    SBAR;
    WAITL0;
    __builtin_amdgcn_s_setprio(1);
#pragma unroll
    for (int mi = 0; mi < 4; ++mi)
#pragma unroll
      for (int ni = 0; ni < 4; ++ni)
        acc[mi][ni] = __builtin_amdgcn_mfma_f32_16x16x32_bf16(
            av[mi], bv[ni], acc[mi][ni], 0, 0, 0);
    __builtin_amdgcn_s_setprio(0);
    SBAR;
    // ---- phase 1: frags (A mi4-7), reuse B
#pragma unroll
    for (int i = 0; i < 4; ++i)
      av[i] = *(const bf16x8*)(bufp + abase + 4096 + i * 1024);
    SBAR;
    WAITL0;
    __builtin_amdgcn_s_setprio(1);
#pragma unroll
    for (int mi = 0; mi < 4; ++mi)
#pragma unroll
      for (int ni = 0; ni < 4; ++ni)
        acc[4 + mi][ni] = __builtin_amdgcn_mfma_f32_16x16x32_bf16(
            av[mi], bv[ni], acc[4 + mi][ni], 0, 0, 0);
    __builtin_amdgcn_s_setprio(0);
    WAITV(4);  // tile tt+1 fully landed for every wave after the barrier
    SBAR;
  }

  // epilogue: drain, then compute tiles NT-2, NT-1 (no more LDS writers)
  WAITV(0);
  SBAR;
#pragma unroll
  for (int e = 0; e < 2; ++e) {
    const char* bufp = lds + ((NT - 2 + e) & 3) * 32768;
#pragma unroll
    for (int i = 0; i < 4; ++i) {
      av[i] = *(const bf16x8*)(bufp + abase + i * 1024);
      bv[i] = *(const bf16x8*)(bufp + bbase + i * 1024);
    }
#pragma unroll
    for (int mi = 0; mi < 4; ++mi)
#pragma unroll
      for (int ni = 0; ni < 4; ++ni)
        acc[mi][ni] = __builtin_amdgcn_mfma_f32_16x16x32_bf16(
            av[mi], bv[ni], acc[mi][ni], 0, 0, 0);
#pragma unroll
    for (int i = 0; i < 4; ++i)
      av[i] = *(const bf16x8*)(bufp + abase + 4096 + i * 1024);
#pragma unroll
    for (int mi = 0; mi < 4; ++mi)
#pragma unroll
      for (int ni = 0; ni < 4; ++ni)
        acc[4 + mi][ni] = __builtin_amdgcn_mfma_f32_16x16x32_bf16(
            av[mi], bv[ni], acc[4 + mi][ni], 0, 0, 0);
  }

  // C-write. C/D layout: col = lane&15, row = (lane>>4)*4 + j [m89-verified]
  const float* nrmz = (MODE == 4) ? (norm + z * normOffZ) : nullptr;
  float* Cf = (float*)C + z * cOffZ;
  unsigned short* Cu = (unsigned short*)C + z * cOffZ;
#pragma unroll
  for (int mi = 0; mi < 8; ++mi) {
    const int rbase = m0 + wm * 128 + mi * 16 + fq * 4;
    float rb[4], nv[4];
#pragma unroll
    for (int j = 0; j < 4; ++j) {
      if (MODE == 1 || MODE == 2) rb[j] = bias[rbase + j];
      if (MODE == 4) nv[j] = nrmz[rbase + j];
    }
#pragma unroll
    for (int ni = 0; ni < 4; ++ni) {
      const int c = n0 + wn * 64 + ni * 16 + fr;
      float cb = 0.f;
      if (MODE == 0) cb = bias[c];
#pragma unroll
      for (int j = 0; j < 4; ++j) {
        float v = acc[mi][ni][j];
        if (MODE == 0) v += cb;
        if (MODE == 1 || MODE == 2) v += rb[j];
        if (MODE == 0 || MODE == 1) v = (v > 0.f) ? v + 1.f : __expf(v);
        const long long ci = (long long)(rbase + j) * ldc + c;
        if (MODE == 4)
          Cf[ci] = v / nv[j];
        else
          Cu[ci] = f2bf(v);
      }
    }
  }
}

// W [1024(in)][1024(out)] f32  ->  WT [1024(out)][1024(in)] bf16
__global__ __launch_bounds__(256) void transpose_w(
    const float* __restrict__ W, unsigned short* __restrict__ WT) {
  __shared__ float tile[32][33];
  const int tx = threadIdx.x & 31, ty = threadIdx.x >> 5;
  const int i0 = blockIdx.y * 32, o0 = blockIdx.x * 32;
#pragma unroll
  for (int s = 0; s < 32; s += 8)
    tile[ty + s][tx] = W[(long long)(i0 + ty + s) * 1024 + o0 + tx];
  __syncthreads();
#pragma unroll
  for (int s = 0; s < 32; s += 8)
    WT[(long long)(o0 + ty + s) * 1024 + i0 + tx] = f2bf(tile[tx][ty + s]);
}

__global__ __launch_bounds__(256) void convert_x(
    const float4* __restrict__ in, uint2* __restrict__ out, int n4) {
  const int stride = gridDim.x * blockDim.x;
  for (int i = blockIdx.x * blockDim.x + threadIdx.x; i < n4; i += stride) {
    float4 v = in[i];
    uint2 o;
    o.x = (unsigned)f2bf(v.x) | ((unsigned)f2bf(v.y) << 16);
    o.y = (unsigned)f2bf(v.z) | ((unsigned)f2bf(v.w) << 16);
    out[i] = o;
  }
}

// K_sum[b][d] = sum_n KpT[d][b*4096 + n]   (one wave per (b,d))
__global__ __launch_bounds__(256) void ksum_kernel(
    const unsigned short* __restrict__ KpT, float* __restrict__ Ksum) {
  const int gw = (blockIdx.x * 256 + threadIdx.x) >> 6;  // 0..4095
  const int lane = threadIdx.x & 63;
  const int d = gw >> 2, b = gw & 3;
  const unsigned short* p = KpT + (long long)d * 16384 + b * 4096;
  float s = 0.f;
  for (int i = lane; i < 4096; i += 64) s += bf2f(p[i]);
#pragma unroll
  for (int o = 32; o > 0; o >>= 1) s += __shfl_down(s, o, 64);
  if (lane == 0) Ksum[b * 1024 + d] = s;
}

// nrm[m] = eps + sum_d Qp[m][d] * Ksum[b][d]   (one wave per row m)
__global__ __launch_bounds__(256) void norm_kernel(
    const unsigned short* __restrict__ Qp, const float* __restrict__ Ksum,
    float* __restrict__ nrm) {
  const int gw = (blockIdx.x * 256 + threadIdx.x) >> 6;  // 0..16383
  const int lane = threadIdx.x & 63;
  const int b = gw >> 12;
  const unsigned short* q = Qp + (long long)gw * 1024;
  const float* ks = Ksum + b * 1024;
  float s = 0.f;
  for (int i = lane; i < 1024; i += 64) s += bf2f(q[i]) * ks[i];
#pragma unroll
  for (int o = 32; o > 0; o >>= 1) s += __shfl_down(s, o, 64);
  if (lane == 0) nrm[gw] = s + 1e-6f;
}

extern "C" void kernel_launch(void* const* d_in, const int* in_sizes, int n_in,
                              void* d_out, int out_size, void* d_ws,
                              size_t ws_size, hipStream_t stream) {
  const float* x  = (const float*)d_in[0];
  const float* Wq = (const float*)d_in[1];
  const float* bq = (const float*)d_in[2];
  const float* Wk = (const float*)d_in[3];
  const float* bk = (const float*)d_in[4];
  const float* Wv = (const float*)d_in[5];
  const float* bv = (const float*)d_in[6];
  float* out = (float*)d_out;

  const size_t MN = 16384ull * 1024ull;  // B*N*D elements
  char* w = (char*)d_ws;
  unsigned short* xb  = (unsigned short*)w;  w += MN * 2;                 // x bf16 [16384][1024]
  unsigned short* WT  = (unsigned short*)w;  w += 3ull * 1024 * 1024 * 2; // Wq^T|Wk^T|Wv^T bf16
  unsigned short* Qp  = (unsigned short*)w;  w += MN * 2;                 // [16384][1024]
  unsigned short* KpT = (unsigned short*)w;  w += MN * 2;                 // [1024][16384]
  unsigned short* VT  = (unsigned short*)w;  w += MN * 2;                 // [1024][16384]
  unsigned short* KVt = (unsigned short*)w;  w += 4ull * 1024 * 1024 * 2; // [4][1024(e)][1024(d)]
  float* Ksum = (float*)w;  w += 4ull * 1024 * 4;                         // [4][1024]
  float* nrm  = (float*)w;  w += 16384ull * 4;                            // [16384]

  transpose_w<<<dim3(32, 32), 256, 0, stream>>>(Wq, WT);
  transpose_w<<<dim3(32, 32), 256, 0, stream>>>(Wk, WT + 1024 * 1024);
  transpose_w<<<dim3(32, 32), 256, 0, stream>>>(Wv, WT + 2 * 1024 * 1024);
  convert_x<<<2048, 256, 0, stream>>>((const float4*)x, (uint2*)xb,
                                      (int)(MN / 4));

  // Qp = elu(x @ Wq + bq)+1 : A=xb[16384][1024], Bt=WqT[1024][1024]
  gemm256<0><<<dim3(4, 64, 1), 512, 0, stream>>>(
      xb, 1024, 0, WT, 1024, 0, Qp, 1024, 0, bq, nullptr, 0, 1024);
  // KpT = (elu(x @ Wk + bk)+1)^T : A=WkT[1024][1024], Bt=xb[16384][1024]
  gemm256<1><<<dim3(64, 4, 1), 512, 0, stream>>>(
      WT + 1024 * 1024, 1024, 0, xb, 1024, 0, KpT, 16384, 0, bk, nullptr, 0,
      1024);
  // VT = (x @ Wv + bv)^T
  gemm256<2><<<dim3(64, 4, 1), 512, 0, stream>>>(
      WT + 2 * 1024 * 1024, 1024, 0, xb, 1024, 0, VT, 16384, 0, bv, nullptr, 0,
      1024);
  ksum_kernel<<<1024, 256, 0, stream>>>(KpT, Ksum);
  // KVt[b][e][d] = sum_n VT[e][bn] * KpT[d][bn]  (K=4096 per batch z)
  gemm256<3><<<dim3(4, 4, 4), 512, 0, stream>>>(
      VT, 16384, 4096, KpT, 16384, 4096, KVt, 1024, 1024 * 1024, nullptr,
      nullptr, 0, 4096);
  norm_kernel<<<4096, 256, 0, stream>>>(Qp, Ksum, nrm);
  // out[b][n][e] = (sum_d Qp[bn][d] * KVt[b][e][d]) / nrm[bn]
  gemm256<4><<<dim3(4, 16, 4), 512, 0, stream>>>(
      Qp, 1024, 4096ll * 1024, KVt, 1024, 1024 * 1024, out, 1024,
      4096ll * 1024, nullptr, nrm, 4096, 1024);
}

// Round 3
// 275.887 us; speedup vs baseline: 1.4878x; 1.2156x over previous
//
#include <hip/hip_runtime.h>
#include <hip/hip_bf16.h>
#include <cstdint>

typedef __bf16 bf16x8 __attribute__((ext_vector_type(8)));
typedef float  f32x4  __attribute__((ext_vector_type(4)));
typedef unsigned short u16x8 __attribute__((ext_vector_type(8)));

__device__ __forceinline__ unsigned short f2bf(float f) {
  __hip_bfloat16 h = __float2bfloat16(f);
  return __builtin_bit_cast(unsigned short, h);
}
__device__ __forceinline__ float bf2f(unsigned short u) {
  return __builtin_bit_cast(float, (unsigned)u << 16);
}

#define GL2LDS16(gp, lp)                                                      \
  __builtin_amdgcn_global_load_lds(                                           \
      (const __attribute__((address_space(1))) unsigned int*)(gp),            \
      (__attribute__((address_space(3))) unsigned int*)(lp), 16, 0, 0)

#define SBAR                                                                  \
  {                                                                           \
    __builtin_amdgcn_s_barrier();                                             \
    __builtin_amdgcn_sched_barrier(0);                                        \
  }
#define WAITV(n)                                                              \
  {                                                                           \
    asm volatile("s_waitcnt vmcnt(" #n ")" ::: "memory");                     \
    __builtin_amdgcn_sched_barrier(0);                                        \
  }
#define WAITL0                                                                \
  {                                                                           \
    asm volatile("s_waitcnt lgkmcnt(0)" ::: "memory");                        \
    __builtin_amdgcn_sched_barrier(0);                                        \
  }

// 256x256-tile GEMM, C[m][n] = sum_k A[m][k]*B[n][k] (B transposed layout).
// BK=32, 8 waves (2Mx4N), per-wave 128x64 output = acc[8][4] of 16x16 frags.
// 4-deep LDS K-tile ring (4 x 32KB), lookahead-3 counted-vmcnt pipeline:
// stage(t+3) in phase0, WAITV(8) at tile end (12 outstanding -> oldest tile
// drained; never vmcnt(0) in the loop). LDS swizzle phys = l ^ (((l>>7)&3)<<4)
// applied on BOTH pre-swizzled global source and ds_read address (rule #21).
// Modes: 0 Qp (col bias+elu+1, bf16)
//        1 merged KV-proj (rows<1024: bias+elu+1 -> KpT; rows>=1024: bias2 -> VT)
//        3 split-K KVt partial (z = ks*4+b; K-window = b*4096+ks*1024; bf16)
//        4 numerator (f32 out, /norm[row])
template <int MODE>
__global__ __launch_bounds__(512, 2) void gemm256(
    const unsigned short* __restrict__ A, long long lda, long long aOffZ,
    const unsigned short* __restrict__ B, long long ldb, long long bOffZ,
    void* __restrict__ C, long long ldc, long long cOffZ,
    const float* __restrict__ bias, const float* __restrict__ bias2,
    const float* __restrict__ norm, long long normOffZ, int K) {
  __shared__ __attribute__((aligned(16))) char lds[4 * 32768];
  const int t = threadIdx.x;
  const int wave = t >> 6, lane = t & 63;
  const int wm = wave >> 2, wn = wave & 3;
  const int fr = lane & 15, fq = lane >> 4;

  // bijective XCD swizzle on flat xy block id (all grids here are %8==0)
  const int gx = gridDim.x, gy = gridDim.y;
  int flat = blockIdx.y * gx + blockIdx.x;
  const int total = gx * gy;
  if ((total & 7) == 0) flat = (flat & 7) * (total >> 3) + (flat >> 3);
  const int bx = flat % gx, by = flat / gx;
  const int m0 = by * 256, n0 = bx * 256;

  const long long z = blockIdx.z;
  long long aBase, bBase;
  if (MODE == 3) {
    const long long koff = (z & 3) * 4096 + (z >> 2) * 1024;
    aBase = koff;
    bBase = koff;
  } else {
    aBase = z * aOffZ;
    bBase = z * bOffZ;
  }
  const unsigned short* Az = A + aBase;
  const unsigned short* Bz = B + bBase;

  // staging: thread t's 16B lands at linear LDS byte d = c*8192 + t*16;
  // content there must be logical byte l = d ^ (((d>>7)&3)<<4).
  const unsigned short* gA[2];
  const unsigned short* gB[2];
#pragma unroll
  for (int c = 0; c < 2; ++c) {
    int d = c * 8192 + t * 16;
    int l = d ^ (((d >> 7) & 3) << 4);
    int row = l >> 6, kel = (l & 63) >> 1;
    gA[c] = Az + (long long)(m0 + row) * lda + kel;
    gB[c] = Bz + (long long)(n0 + row) * ldb + kel;
  }

  // fragment read offsets (physical, swizzle folded in; lane-constant XOR)
  const int slotx = (fr >> 1) & 3;
  const int abase = wm * 8192 + fr * 64 + ((fq ^ slotx) << 4);
  const int bbase = 16384 + wn * 4096 + fr * 64 + ((fq ^ slotx) << 4);

  f32x4 acc[8][4];
#pragma unroll
  for (int i = 0; i < 8; ++i)
#pragma unroll
    for (int j = 0; j < 4; ++j) acc[i][j] = (f32x4){0.f, 0.f, 0.f, 0.f};

  const int NT = K >> 5;

  auto stage = [&](int tile) {
    const int k0 = tile << 5;
    char* bufp = lds + (tile & 3) * 32768;
#pragma unroll
    for (int c = 0; c < 2; ++c)
      GL2LDS16(gA[c] + k0, bufp + c * 8192 + wave * 1024);
#pragma unroll
    for (int c = 0; c < 2; ++c)
      GL2LDS16(gB[c] + k0, bufp + 16384 + c * 8192 + wave * 1024);
  };

  stage(0);
  stage(1);
  stage(2);
  WAITV(8);  // tile 0 landed (tiles 1,2 may be outstanding)
  SBAR;

  bf16x8 av[4], bv[4];
  for (int tt = 0; tt < NT - 3; ++tt) {
    const char* bufp = lds + (tt & 3) * 32768;
    // ---- phase 0: frags (A mi0-3, B ni0-3) + prefetch tile tt+3
#pragma unroll
    for (int i = 0; i < 4; ++i) {
      av[i] = *(const bf16x8*)(bufp + abase + i * 1024);
      bv[i] = *(const bf16x8*)(bufp + bbase + i * 1024);
    }
    stage(tt + 3);
    SBAR;
    WAITL0;
    __builtin_amdgcn_s_setprio(1);
#pragma unroll
    for (int mi = 0; mi < 4; ++mi)
#pragma unroll
      for (int ni = 0; ni < 4; ++ni)
        acc[mi][ni] = __builtin_amdgcn_mfma_f32_16x16x32_bf16(
            av[mi], bv[ni], acc[mi][ni], 0, 0, 0);
    __builtin_amdgcn_s_setprio(0);
    SBAR;
    // ---- phase 1: frags (A mi4-7), reuse B
#pragma unroll
    for (int i = 0; i < 4; ++i)
      av[i] = *(const bf16x8*)(bufp + abase + 4096 + i * 1024);
    SBAR;
    WAITL0;
    __builtin_amdgcn_s_setprio(1);
#pragma unroll
    for (int mi = 0; mi < 4; ++mi)
#pragma unroll
      for (int ni = 0; ni < 4; ++ni)
        acc[4 + mi][ni] = __builtin_amdgcn_mfma_f32_16x16x32_bf16(
            av[mi], bv[ni], acc[4 + mi][ni], 0, 0, 0);
    __builtin_amdgcn_s_setprio(0);
    WAITV(8);  // tile tt+1 fully landed for every wave after the barrier
    SBAR;
  }

  // tail: drain, then compute tiles NT-3..NT-1 (no more LDS writers)
  WAITV(0);
  SBAR;
#pragma unroll
  for (int e = 0; e < 3; ++e) {
    const char* bufp = lds + ((NT - 3 + e) & 3) * 32768;
#pragma unroll
    for (int i = 0; i < 4; ++i) {
      av[i] = *(const bf16x8*)(bufp + abase + i * 1024);
      bv[i] = *(const bf16x8*)(bufp + bbase + i * 1024);
    }
#pragma unroll
    for (int mi = 0; mi < 4; ++mi)
#pragma unroll
      for (int ni = 0; ni < 4; ++ni)
        acc[mi][ni] = __builtin_amdgcn_mfma_f32_16x16x32_bf16(
            av[mi], bv[ni], acc[mi][ni], 0, 0, 0);
#pragma unroll
    for (int i = 0; i < 4; ++i)
      av[i] = *(const bf16x8*)(bufp + abase + 4096 + i * 1024);
#pragma unroll
    for (int mi = 0; mi < 4; ++mi)
#pragma unroll
      for (int ni = 0; ni < 4; ++ni)
        acc[4 + mi][ni] = __builtin_amdgcn_mfma_f32_16x16x32_bf16(
            av[mi], bv[ni], acc[4 + mi][ni], 0, 0, 0);
  }

  // C-write. C/D layout: col = lane&15, row = (lane>>4)*4 + j [m89-verified]
  const float* nrmz = (MODE == 4) ? (norm + z * normOffZ) : nullptr;
  float* Cf = (float*)C + z * cOffZ;
  unsigned short* Cu = (unsigned short*)C + z * cOffZ;
  const bool lower = (m0 < 1024);  // block-uniform (MODE 1: KpT vs VT half)
#pragma unroll
  for (int mi = 0; mi < 8; ++mi) {
    const int rbase = m0 + wm * 128 + mi * 16 + fq * 4;
    float rb[4], nv[4];
#pragma unroll
    for (int j = 0; j < 4; ++j) {
      if (MODE == 1)
        rb[j] = lower ? bias[rbase + j] : bias2[rbase - 1024 + j];
      if (MODE == 4) nv[j] = nrmz[rbase + j];
    }
#pragma unroll
    for (int ni = 0; ni < 4; ++ni) {
      const int c = n0 + wn * 64 + ni * 16 + fr;
      float cb = 0.f;
      if (MODE == 0) cb = bias[c];
#pragma unroll
      for (int j = 0; j < 4; ++j) {
        float v = acc[mi][ni][j];
        if (MODE == 0) v += cb;
        if (MODE == 1) v += rb[j];
        if (MODE == 0 || (MODE == 1 && lower))
          v = (v > 0.f) ? v + 1.f : __expf(v);
        const long long ci = (long long)(rbase + j) * ldc + c;
        if (MODE == 4)
          Cf[ci] = v / nv[j];
        else
          Cu[ci] = f2bf(v);
      }
    }
  }
}

// KVt[b][e][d] = sum_ks P[ks*4+b][e][d]   (P: [16][1024][1024] bf16 partials)
__global__ __launch_bounds__(256) void reduce_kvt(
    const unsigned short* __restrict__ P, unsigned short* __restrict__ KVt) {
  const long long i = ((long long)blockIdx.x * 256 + threadIdx.x) * 8;
  const int b = (int)(i >> 20);
  const long long ed = i & ((1ll << 20) - 1);
  float s[8] = {0.f, 0.f, 0.f, 0.f, 0.f, 0.f, 0.f, 0.f};
#pragma unroll
  for (int ks = 0; ks < 4; ++ks) {
    u16x8 v = *(const u16x8*)(P + ((long long)(ks * 4 + b) << 20) + ed);
#pragma unroll
    for (int j = 0; j < 8; ++j) s[j] += bf2f(v[j]);
  }
  u16x8 o;
#pragma unroll
  for (int j = 0; j < 8; ++j) o[j] = f2bf(s[j]);
  *(u16x8*)(KVt + i) = o;
}

// W [1024(in)][1024(out)] f32  ->  WT [1024(out)][1024(in)] bf16
__global__ __launch_bounds__(256) void transpose_w(
    const float* __restrict__ W, unsigned short* __restrict__ WT) {
  __shared__ float tile[32][33];
  const int tx = threadIdx.x & 31, ty = threadIdx.x >> 5;
  const int i0 = blockIdx.y * 32, o0 = blockIdx.x * 32;
#pragma unroll
  for (int s = 0; s < 32; s += 8)
    tile[ty + s][tx] = W[(long long)(i0 + ty + s) * 1024 + o0 + tx];
  __syncthreads();
#pragma unroll
  for (int s = 0; s < 32; s += 8)
    WT[(long long)(o0 + ty + s) * 1024 + i0 + tx] = f2bf(tile[tx][ty + s]);
}

__global__ __launch_bounds__(256) void convert_x(
    const float4* __restrict__ in, uint2* __restrict__ out, int n4) {
  const int stride = gridDim.x * blockDim.x;
  for (int i = blockIdx.x * blockDim.x + threadIdx.x; i < n4; i += stride) {
    float4 v = in[i];
    uint2 o;
    o.x = (unsigned)f2bf(v.x) | ((unsigned)f2bf(v.y) << 16);
    o.y = (unsigned)f2bf(v.z) | ((unsigned)f2bf(v.w) << 16);
    out[i] = o;
  }
}

// K_sum[b][d] = sum_n KpT[d][b*4096 + n]   (one wave per (b,d))
__global__ __launch_bounds__(256) void ksum_kernel(
    const unsigned short* __restrict__ KpT, float* __restrict__ Ksum) {
  const int gw = (blockIdx.x * 256 + threadIdx.x) >> 6;  // 0..4095
  const int lane = threadIdx.x & 63;
  const int d = gw >> 2, b = gw & 3;
  const unsigned short* p = KpT + (long long)d * 16384 + b * 4096;
  float s = 0.f;
  for (int i = lane; i < 4096; i += 64) s += bf2f(p[i]);
#pragma unroll
  for (int o = 32; o > 0; o >>= 1) s += __shfl_down(s, o, 64);
  if (lane == 0) Ksum[b * 1024 + d] = s;
}

// nrm[m] = eps + sum_d Qp[m][d] * Ksum[b][d]   (one wave per row m)
__global__ __launch_bounds__(256) void norm_kernel(
    const unsigned short* __restrict__ Qp, const float* __restrict__ Ksum,
    float* __restrict__ nrm) {
  const int gw = (blockIdx.x * 256 + threadIdx.x) >> 6;  // 0..16383
  const int lane = threadIdx.x & 63;
  const int b = gw >> 12;
  const unsigned short* q = Qp + (long long)gw * 1024;
  const float* ks = Ksum + b * 1024;
  float s = 0.f;
  for (int i = lane; i < 1024; i += 64) s += bf2f(q[i]) * ks[i];
#pragma unroll
  for (int o = 32; o > 0; o >>= 1) s += __shfl_down(s, o, 64);
  if (lane == 0) nrm[gw] = s + 1e-6f;
}

extern "C" void kernel_launch(void* const* d_in, const int* in_sizes, int n_in,
                              void* d_out, int out_size, void* d_ws,
                              size_t ws_size, hipStream_t stream) {
  const float* x  = (const float*)d_in[0];
  const float* Wq = (const float*)d_in[1];
  const float* bq = (const float*)d_in[2];
  const float* Wk = (const float*)d_in[3];
  const float* bk = (const float*)d_in[4];
  const float* Wv = (const float*)d_in[5];
  const float* bv = (const float*)d_in[6];
  float* out = (float*)d_out;

  const size_t MN = 16384ull * 1024ull;  // B*N*D elements
  char* w = (char*)d_ws;
  unsigned short* xb  = (unsigned short*)w;  w += MN * 2;                 // x bf16 [16384][1024]; dead after projections -> reused as KVt partials [16][1024][1024]
  unsigned short* WT  = (unsigned short*)w;  w += 3ull * 1024 * 1024 * 2; // Wq^T|Wk^T|Wv^T bf16
  unsigned short* Qp  = (unsigned short*)w;  w += MN * 2;                 // [16384][1024]
  unsigned short* KVb = (unsigned short*)w;  w += 2 * MN * 2;            // [2048][16384]: rows 0-1023 KpT, 1024-2047 VT
  unsigned short* KVt = (unsigned short*)w;  w += 4ull * 1024 * 1024 * 2; // [4][1024(e)][1024(d)]
  float* Ksum = (float*)w;  w += 4ull * 1024 * 4;                         // [4][1024]
  float* nrm  = (float*)w;  w += 16384ull * 4;                            // [16384]
  unsigned short* Pkv = xb;  // split-K KVt partials, aliases dead xb
  unsigned short* KpT = KVb;
  unsigned short* VT  = KVb + MN;

  transpose_w<<<dim3(32, 32), 256, 0, stream>>>(Wq, WT);
  transpose_w<<<dim3(32, 32), 256, 0, stream>>>(Wk, WT + 1024 * 1024);
  transpose_w<<<dim3(32, 32), 256, 0, stream>>>(Wv, WT + 2 * 1024 * 1024);
  convert_x<<<2048, 256, 0, stream>>>((const float4*)x, (uint2*)xb,
                                      (int)(MN / 4));

  // Qp = elu(x @ Wq + bq)+1 : A=xb[16384][1024], Bt=WqT[1024][1024]
  gemm256<0><<<dim3(4, 64, 1), 512, 0, stream>>>(
      xb, 1024, 0, WT, 1024, 0, Qp, 1024, 0, bq, nullptr, nullptr, 0, 1024);
  // merged K/V projection: A=[WkT;WvT][2048][1024], Bt=xb[16384][1024]
  //   rows <1024: KpT = elu(.)+1 + bk ; rows >=1024: VT = . + bv
  gemm256<1><<<dim3(64, 8, 1), 512, 0, stream>>>(
      WT + 1024 * 1024, 1024, 0, xb, 1024, 0, KVb, 16384, 0, bk, bv, nullptr,
      0, 1024);
  ksum_kernel<<<1024, 256, 0, stream>>>(KpT, Ksum);
  // split-K KVt partials: z = ks*4+b; P[z][e][d] = sum_{n in ks-chunk} VT[e][bn]*KpT[d][bn]
  gemm256<3><<<dim3(4, 4, 16), 512, 0, stream>>>(
      VT, 16384, 0, KpT, 16384, 0, Pkv, 1024, 1024 * 1024, nullptr, nullptr,
      nullptr, 0, 1024);
  reduce_kvt<<<2048, 256, 0, stream>>>(Pkv, KVt);
  norm_kernel<<<4096, 256, 0, stream>>>(Qp, Ksum, nrm);
  // out[b][n][e] = (sum_d Qp[bn][d] * KVt[b][e][d]) / nrm[bn]
  gemm256<4><<<dim3(4, 16, 4), 512, 0, stream>>>(
      Qp, 1024, 4096ll * 1024, KVt, 1024, 1024 * 1024, out, 1024,
      4096ll * 1024, nullptr, nullptr, nrm, 4096, 1024);
}

// Round 4
// 271.598 us; speedup vs baseline: 1.5113x; 1.0158x over previous
//
#include <hip/hip_runtime.h>
#include <hip/hip_bf16.h>
#include <cstdint>

typedef __bf16 bf16x8 __attribute__((ext_vector_type(8)));
typedef float  f32x4  __attribute__((ext_vector_type(4)));
typedef unsigned short u16x8 __attribute__((ext_vector_type(8)));

__device__ __forceinline__ unsigned short f2bf(float f) {
  __hip_bfloat16 h = __float2bfloat16(f);
  return __builtin_bit_cast(unsigned short, h);
}
__device__ __forceinline__ float bf2f(unsigned short u) {
  return __builtin_bit_cast(float, (unsigned)u << 16);
}

#define GL2LDS16(gp, lp)                                                      \
  __builtin_amdgcn_global_load_lds(                                           \
      (const __attribute__((address_space(1))) unsigned int*)(gp),            \
      (__attribute__((address_space(3))) unsigned int*)(lp), 16, 0, 0)

#define SBAR                                                                  \
  {                                                                           \
    __builtin_amdgcn_s_barrier();                                             \
    __builtin_amdgcn_sched_barrier(0);                                        \
  }
#define WAITV(n)                                                              \
  {                                                                           \
    asm volatile("s_waitcnt vmcnt(" #n ")" ::: "memory");                     \
    __builtin_amdgcn_sched_barrier(0);                                        \
  }
#define WAITL0                                                                \
  {                                                                           \
    asm volatile("s_waitcnt lgkmcnt(0)" ::: "memory");                        \
    __builtin_amdgcn_sched_barrier(0);                                        \
  }

// 256x256-tile GEMM, C[m][n] = sum_k A[m][k]*B[n][k] (B transposed layout).
// BK=32, 8 waves (2Mx4N), per-wave 128x64 output = acc[8][4] of 16x16 frags.
// 4-deep LDS K-tile ring, lookahead-3 counted-vmcnt pipeline, single merged
// phase per K-tile: {12 ds_read; stage(t+3); SBAR; lgkm(0); 32 MFMA; vmcnt(8);
// SBAR} -> 2 barriers per 32 MFMA; never vmcnt(0) in the loop.
// LDS swizzle phys = l ^ (((l>>7)&3)<<4) on BOTH pre-swizzled global source
// and ds_read address (rule #21).
// XCD decode: MODE 1 (small A, huge N) chunks column-stripes per XCD so the
// whole A (4MB) stays L2-resident; other modes chunk row-stripes.
// Modes: 0 Qp (col bias+elu+1, bf16)
//        1 merged KV-proj (rows<1024: bias+elu+1 -> KpT, fused ksum atomics;
//                          rows>=1024: bias2 -> VT)
//        3 split-K KVt partial (z = ks*4+b; K-window = b*4096+ks*1024; bf16)
//        4 numerator (f32 out, /norm[row])
template <int MODE>
__global__ __launch_bounds__(512, 2) void gemm256(
    const unsigned short* __restrict__ A, long long lda, long long aOffZ,
    const unsigned short* __restrict__ B, long long ldb, long long bOffZ,
    void* __restrict__ C, long long ldc, long long cOffZ,
    const float* __restrict__ bias, const float* __restrict__ bias2,
    const float* __restrict__ norm, long long normOffZ,
    float* __restrict__ ksum, int K) {
  __shared__ __attribute__((aligned(16))) char lds[4 * 32768];
  const int t = threadIdx.x;
  const int wave = t >> 6, lane = t & 63;
  const int wm = wave >> 2, wn = wave & 3;
  const int fr = lane & 15, fq = lane >> 4;

  // bijective XCD swizzle on flat xy block id (all grids here are %8==0)
  const int gx = gridDim.x, gy = gridDim.y;
  int flat = blockIdx.y * gx + blockIdx.x;
  const int total = gx * gy;
  if ((total & 7) == 0) flat = (flat & 7) * (total >> 3) + (flat >> 3);
  int bx, by;
  if (MODE == 1) {  // column-major decode: XCD owns few bx across all by
    bx = flat / gy;
    by = flat - bx * gy;
  } else {
    bx = flat % gx;
    by = flat / gx;
  }
  const int m0 = by * 256, n0 = bx * 256;

  const long long z = blockIdx.z;
  long long aBase, bBase;
  if (MODE == 3) {
    const long long koff = (z & 3) * 4096 + (z >> 2) * 1024;
    aBase = koff;
    bBase = koff;
  } else {
    aBase = z * aOffZ;
    bBase = z * bOffZ;
  }
  const unsigned short* Az = A + aBase;
  const unsigned short* Bz = B + bBase;

  // staging: thread t's 16B lands at linear LDS byte d = c*8192 + t*16;
  // content there must be logical byte l = d ^ (((d>>7)&3)<<4).
  const unsigned short* gA[2];
  const unsigned short* gB[2];
#pragma unroll
  for (int c = 0; c < 2; ++c) {
    int d = c * 8192 + t * 16;
    int l = d ^ (((d >> 7) & 3) << 4);
    int row = l >> 6, kel = (l & 63) >> 1;
    gA[c] = Az + (long long)(m0 + row) * lda + kel;
    gB[c] = Bz + (long long)(n0 + row) * ldb + kel;
  }

  // fragment read offsets (physical, swizzle folded in; lane-constant XOR)
  const int slotx = (fr >> 1) & 3;
  const int abase = wm * 8192 + fr * 64 + ((fq ^ slotx) << 4);
  const int bbase = 16384 + wn * 4096 + fr * 64 + ((fq ^ slotx) << 4);

  f32x4 acc[8][4];
#pragma unroll
  for (int i = 0; i < 8; ++i)
#pragma unroll
    for (int j = 0; j < 4; ++j) acc[i][j] = (f32x4){0.f, 0.f, 0.f, 0.f};

  const int NT = K >> 5;

  auto stage = [&](int tile) {
    const int k0 = tile << 5;
    char* bufp = lds + (tile & 3) * 32768;
#pragma unroll
    for (int c = 0; c < 2; ++c)
      GL2LDS16(gA[c] + k0, bufp + c * 8192 + wave * 1024);
#pragma unroll
    for (int c = 0; c < 2; ++c)
      GL2LDS16(gB[c] + k0, bufp + 16384 + c * 8192 + wave * 1024);
  };

  stage(0);
  stage(1);
  stage(2);
  WAITV(8);  // tile 0 landed (tiles 1,2 may be outstanding)
  SBAR;

  bf16x8 av[8], bv[4];
  for (int tt = 0; tt < NT - 3; ++tt) {
    const char* bufp = lds + (tt & 3) * 32768;
#pragma unroll
    for (int i = 0; i < 4; ++i) {
      av[i] = *(const bf16x8*)(bufp + abase + i * 1024);
      av[4 + i] = *(const bf16x8*)(bufp + abase + 4096 + i * 1024);
      bv[i] = *(const bf16x8*)(bufp + bbase + i * 1024);
    }
    stage(tt + 3);
    SBAR;
    WAITL0;
    __builtin_amdgcn_s_setprio(1);
#pragma unroll
    for (int mi = 0; mi < 8; ++mi)
#pragma unroll
      for (int ni = 0; ni < 4; ++ni)
        acc[mi][ni] = __builtin_amdgcn_mfma_f32_16x16x32_bf16(
            av[mi], bv[ni], acc[mi][ni], 0, 0, 0);
    __builtin_amdgcn_s_setprio(0);
    WAITV(8);  // own loads of tile tt+1 done; barrier makes it global
    SBAR;
  }

  // tail: drain all staging, then compute tiles NT-3..NT-1 (no more writers)
  WAITV(0);
  SBAR;
#pragma unroll
  for (int e = 0; e < 3; ++e) {
    const char* bufp = lds + ((NT - 3 + e) & 3) * 32768;
#pragma unroll
    for (int i = 0; i < 4; ++i) {
      av[i] = *(const bf16x8*)(bufp + abase + i * 1024);
      av[4 + i] = *(const bf16x8*)(bufp + abase + 4096 + i * 1024);
      bv[i] = *(const bf16x8*)(bufp + bbase + i * 1024);
    }
#pragma unroll
    for (int mi = 0; mi < 8; ++mi)
#pragma unroll
      for (int ni = 0; ni < 4; ++ni)
        acc[mi][ni] = __builtin_amdgcn_mfma_f32_16x16x32_bf16(
            av[mi], bv[ni], acc[mi][ni], 0, 0, 0);
  }

  // C-write. C/D layout: col = lane&15, row = (lane>>4)*4 + j [m89-verified]
  const float* nrmz = (MODE == 4) ? (norm + z * normOffZ) : nullptr;
  float* Cf = (float*)C + z * cOffZ;
  unsigned short* Cu = (unsigned short*)C + z * cOffZ;
  const bool lower = (m0 < 1024);  // block-uniform (MODE 1: KpT vs VT half)
  const int bidx = n0 >> 12;       // MODE 1: batch of this column stripe
#pragma unroll
  for (int mi = 0; mi < 8; ++mi) {
    const int rbase = m0 + wm * 128 + mi * 16 + fq * 4;
    float rb[4], nv[4], ks[4];
#pragma unroll
    for (int j = 0; j < 4; ++j) {
      if (MODE == 1)
        rb[j] = lower ? bias[rbase + j] : bias2[rbase - 1024 + j];
      if (MODE == 4) nv[j] = nrmz[rbase + j];
      ks[j] = 0.f;
    }
#pragma unroll
    for (int ni = 0; ni < 4; ++ni) {
      const int c = n0 + wn * 64 + ni * 16 + fr;
      float cb = 0.f;
      if (MODE == 0) cb = bias[c];
#pragma unroll
      for (int j = 0; j < 4; ++j) {
        float v = acc[mi][ni][j];
        if (MODE == 0) v += cb;
        if (MODE == 1) v += rb[j];
        if (MODE == 0 || (MODE == 1 && lower))
          v = (v > 0.f) ? v + 1.f : __expf(v);
        if (MODE == 1 && lower) ks[j] += v;
        const long long ci = (long long)(rbase + j) * ldc + c;
        if (MODE == 4)
          Cf[ci] = v / nv[j];
        else
          Cu[ci] = f2bf(v);
      }
    }
    if (MODE == 1 && lower) {
      // 16-lane (fr) tree-reduce each row's partial, one atomic per row/wave
#pragma unroll
      for (int j = 0; j < 4; ++j) {
        float s = ks[j];
        s += __shfl_xor(s, 1, 16);
        s += __shfl_xor(s, 2, 16);
        s += __shfl_xor(s, 4, 16);
        s += __shfl_xor(s, 8, 16);
        if (fr == 0) atomicAdd(&ksum[bidx * 1024 + rbase + j], s);
      }
    }
  }
}

// KVt[b][e][d] = sum_ks P[ks*4+b][e][d]   (P: [16][1024][1024] bf16 partials)
__global__ __launch_bounds__(256) void reduce_kvt(
    const unsigned short* __restrict__ P, unsigned short* __restrict__ KVt) {
  const long long i = ((long long)blockIdx.x * 256 + threadIdx.x) * 8;
  const int b = (int)(i >> 20);
  const long long ed = i & ((1ll << 20) - 1);
  float s[8] = {0.f, 0.f, 0.f, 0.f, 0.f, 0.f, 0.f, 0.f};
#pragma unroll
  for (int ks = 0; ks < 4; ++ks) {
    u16x8 v = *(const u16x8*)(P + ((long long)(ks * 4 + b) << 20) + ed);
#pragma unroll
    for (int j = 0; j < 8; ++j) s[j] += bf2f(v[j]);
  }
  u16x8 o;
#pragma unroll
  for (int j = 0; j < 8; ++j) o[j] = f2bf(s[j]);
  *(u16x8*)(KVt + i) = o;
}

// W [1024(in)][1024(out)] f32  ->  WT [1024(out)][1024(in)] bf16
__global__ __launch_bounds__(256) void transpose_w(
    const float* __restrict__ W, unsigned short* __restrict__ WT) {
  __shared__ float tile[32][33];
  const int tx = threadIdx.x & 31, ty = threadIdx.x >> 5;
  const int i0 = blockIdx.y * 32, o0 = blockIdx.x * 32;
#pragma unroll
  for (int s = 0; s < 32; s += 8)
    tile[ty + s][tx] = W[(long long)(i0 + ty + s) * 1024 + o0 + tx];
  __syncthreads();
#pragma unroll
  for (int s = 0; s < 32; s += 8)
    WT[(long long)(o0 + ty + s) * 1024 + i0 + tx] = f2bf(tile[tx][ty + s]);
}

__global__ __launch_bounds__(256) void convert_x(
    const float4* __restrict__ in, uint2* __restrict__ out, int n4) {
  const int stride = gridDim.x * blockDim.x;
  for (int i = blockIdx.x * blockDim.x + threadIdx.x; i < n4; i += stride) {
    float4 v = in[i];
    uint2 o;
    o.x = (unsigned)f2bf(v.x) | ((unsigned)f2bf(v.y) << 16);
    o.y = (unsigned)f2bf(v.z) | ((unsigned)f2bf(v.w) << 16);
    out[i] = o;
  }
}

// nrm[m] = eps + sum_d Qp[m][d] * Ksum[b][d]   (one wave per row m)
__global__ __launch_bounds__(256) void norm_kernel(
    const unsigned short* __restrict__ Qp, const float* __restrict__ Ksum,
    float* __restrict__ nrm) {
  const int gw = (blockIdx.x * 256 + threadIdx.x) >> 6;  // 0..16383
  const int lane = threadIdx.x & 63;
  const int b = gw >> 12;
  const unsigned short* q = Qp + (long long)gw * 1024;
  const float* ks = Ksum + b * 1024;
  float s = 0.f;
  for (int i = lane; i < 1024; i += 64) s += bf2f(q[i]) * ks[i];
#pragma unroll
  for (int o = 32; o > 0; o >>= 1) s += __shfl_down(s, o, 64);
  if (lane == 0) nrm[gw] = s + 1e-6f;
}

extern "C" void kernel_launch(void* const* d_in, const int* in_sizes, int n_in,
                              void* d_out, int out_size, void* d_ws,
                              size_t ws_size, hipStream_t stream) {
  const float* x  = (const float*)d_in[0];
  const float* Wq = (const float*)d_in[1];
  const float* bq = (const float*)d_in[2];
  const float* Wk = (const float*)d_in[3];
  const float* bk = (const float*)d_in[4];
  const float* Wv = (const float*)d_in[5];
  const float* bv = (const float*)d_in[6];
  float* out = (float*)d_out;

  const size_t MN = 16384ull * 1024ull;  // B*N*D elements
  char* w = (char*)d_ws;
  unsigned short* xb  = (unsigned short*)w;  w += MN * 2;                 // x bf16; dead after projections -> reused as KVt partials [16][1024][1024]
  unsigned short* WT  = (unsigned short*)w;  w += 3ull * 1024 * 1024 * 2; // Wq^T|Wk^T|Wv^T bf16
  unsigned short* Qp  = (unsigned short*)w;  w += MN * 2;                 // [16384][1024]
  unsigned short* KVb = (unsigned short*)w;  w += 2 * MN * 2;            // [2048][16384]: rows 0-1023 KpT, 1024-2047 VT
  unsigned short* KVt = (unsigned short*)w;  w += 4ull * 1024 * 1024 * 2; // [4][1024(e)][1024(d)]
  float* Ksum = (float*)w;  w += 4ull * 1024 * 4;                         // [4][1024]
  float* nrm  = (float*)w;  w += 16384ull * 4;                            // [16384]
  unsigned short* Pkv = xb;  // split-K KVt partials, aliases dead xb
  unsigned short* KpT = KVb;
  unsigned short* VT  = KVb + MN;

  hipMemsetAsync(Ksum, 0, 4096 * sizeof(float), stream);
  transpose_w<<<dim3(32, 32), 256, 0, stream>>>(Wq, WT);
  transpose_w<<<dim3(32, 32), 256, 0, stream>>>(Wk, WT + 1024 * 1024);
  transpose_w<<<dim3(32, 32), 256, 0, stream>>>(Wv, WT + 2 * 1024 * 1024);
  convert_x<<<2048, 256, 0, stream>>>((const float4*)x, (uint2*)xb,
                                      (int)(MN / 4));

  // Qp = elu(x @ Wq + bq)+1 : A=xb[16384][1024], Bt=WqT[1024][1024]
  gemm256<0><<<dim3(4, 64, 1), 512, 0, stream>>>(
      xb, 1024, 0, WT, 1024, 0, Qp, 1024, 0, bq, nullptr, nullptr, 0, nullptr,
      1024);
  // merged K/V projection: A=[WkT;WvT][2048][1024], Bt=xb[16384][1024]
  //   rows <1024: KpT = elu(.+bk)+1 (fused ksum); rows >=1024: VT = . + bv
  gemm256<1><<<dim3(64, 8, 1), 512, 0, stream>>>(
      WT + 1024 * 1024, 1024, 0, xb, 1024, 0, KVb, 16384, 0, bk, bv, nullptr,
      0, Ksum, 1024);
  // split-K KVt partials: z = ks*4+b; P[z] = VT[:,win] . KpT[:,win]^T
  gemm256<3><<<dim3(4, 4, 16), 512, 0, stream>>>(
      VT, 16384, 0, KpT, 16384, 0, Pkv, 1024, 1024 * 1024, nullptr, nullptr,
      nullptr, 0, nullptr, 1024);
  reduce_kvt<<<2048, 256, 0, stream>>>(Pkv, KVt);
  norm_kernel<<<4096, 256, 0, stream>>>(Qp, Ksum, nrm);
  // out[b][n][e] = (sum_d Qp[bn][d] * KVt[b][e][d]) / nrm[bn]
  gemm256<4><<<dim3(4, 16, 4), 512, 0, stream>>>(
      Qp, 1024, 4096ll * 1024, KVt, 1024, 1024 * 1024, out, 1024,
      4096ll * 1024, nullptr, nullptr, nrm, 4096, nullptr, 1024);
}

// Round 5
// 254.791 us; speedup vs baseline: 1.6110x; 1.0660x over previous
//
#include <hip/hip_runtime.h>
#include <hip/hip_bf16.h>
#include <cstdint>

typedef __bf16 bf16x8 __attribute__((ext_vector_type(8)));
typedef float  f32x4  __attribute__((ext_vector_type(4)));
typedef unsigned short u16x8 __attribute__((ext_vector_type(8)));

__device__ __forceinline__ unsigned short f2bf(float f) {
  __hip_bfloat16 h = __float2bfloat16(f);
  return __builtin_bit_cast(unsigned short, h);
}
__device__ __forceinline__ float bf2f(unsigned short u) {
  return __builtin_bit_cast(float, (unsigned)u << 16);
}

#define GL2LDS16(gp, lp)                                                      \
  __builtin_amdgcn_global_load_lds(                                           \
      (const __attribute__((address_space(1))) unsigned int*)(gp),            \
      (__attribute__((address_space(3))) unsigned int*)(lp), 16, 0, 0)

#define SBAR                                                                  \
  {                                                                           \
    __builtin_amdgcn_s_barrier();                                             \
    __builtin_amdgcn_sched_barrier(0);                                        \
  }
#define WAITV(n)                                                              \
  {                                                                           \
    asm volatile("s_waitcnt vmcnt(" #n ")" ::: "memory");                     \
    __builtin_amdgcn_sched_barrier(0);                                        \
  }
#define WAITL0                                                                \
  {                                                                           \
    asm volatile("s_waitcnt lgkmcnt(0)" ::: "memory");                        \
    __builtin_amdgcn_sched_barrier(0);                                        \
  }

// 256x256-tile GEMM, C[m][n] = sum_k A[m][k]*B[n][k] (B transposed layout).
// BK=32, 8 waves (2Mx4N), per-wave 128x64 output = acc[8][4] of 16x16 frags.
// 4-deep LDS K-tile ring, lookahead-3, SINGLE barrier per K-tile:
//   {stage(t+3); 12 ds_read(t); lgkm(0); 32 MFMA; vmcnt(8); s_barrier}
// Safety: each wave's lgkm(0) retires its ds_reads BEFORE its barrier, so
// after the barrier no wave still reads buf((t-1)&3) -> stage(t+3) may
// overwrite it. vmcnt(8) (12 outstanding - 8) = own tile-(t+1) loads done;
// barrier globalizes. Never vmcnt(0) in the loop. One barrier per 32 MFMA
// lets waves drift -> ds_read of one wave overlaps MFMA of another (LDS-read
// cost/tile ~= MFMA cost/tile, so this overlap is the main lever).
// LDS swizzle phys = l ^ (((l>>7)&3)<<4) on BOTH pre-swizzled global source
// and ds_read address (rule #21). Bank conflicts measured 0.
// XCD decode: MODE 1 (small A, huge N) chunks column-stripes per XCD so the
// whole A (4MB) stays L2-resident; other modes chunk row-stripes.
// Modes: 0 Qp (col bias+elu+1, bf16)
//        1 merged KV-proj (rows<1024: bias+elu+1 -> KpT; rows>=1024: bias2 -> VT)
//        3 split-K KVt partial (z = ks*4+b; K-window = b*4096+ks*1024; bf16)
//        4 numerator (f32 out, /norm[row])
template <int MODE>
__global__ __launch_bounds__(512, 2) void gemm256(
    const unsigned short* __restrict__ A, long long lda, long long aOffZ,
    const unsigned short* __restrict__ B, long long ldb, long long bOffZ,
    void* __restrict__ C, long long ldc, long long cOffZ,
    const float* __restrict__ bias, const float* __restrict__ bias2,
    const float* __restrict__ norm, long long normOffZ, int K) {
  __shared__ __attribute__((aligned(16))) char lds[4 * 32768];
  const int t = threadIdx.x;
  const int wave = t >> 6, lane = t & 63;
  const int wm = wave >> 2, wn = wave & 3;
  const int fr = lane & 15, fq = lane >> 4;

  // bijective XCD swizzle on flat xy block id (all grids here are %8==0)
  const int gx = gridDim.x, gy = gridDim.y;
  int flat = blockIdx.y * gx + blockIdx.x;
  const int total = gx * gy;
  if ((total & 7) == 0) flat = (flat & 7) * (total >> 3) + (flat >> 3);
  int bx, by;
  if (MODE == 1) {  // column-major decode: XCD owns few bx across all by
    bx = flat / gy;
    by = flat - bx * gy;
  } else {
    bx = flat % gx;
    by = flat / gx;
  }
  const int m0 = by * 256, n0 = bx * 256;

  const long long z = blockIdx.z;
  long long aBase, bBase;
  if (MODE == 3) {
    const long long koff = (z & 3) * 4096 + (z >> 2) * 1024;
    aBase = koff;
    bBase = koff;
  } else {
    aBase = z * aOffZ;
    bBase = z * bOffZ;
  }
  const unsigned short* Az = A + aBase;
  const unsigned short* Bz = B + bBase;

  // staging: thread t's 16B lands at linear LDS byte d = c*8192 + t*16;
  // content there must be logical byte l = d ^ (((d>>7)&3)<<4).
  const unsigned short* gA[2];
  const unsigned short* gB[2];
#pragma unroll
  for (int c = 0; c < 2; ++c) {
    int d = c * 8192 + t * 16;
    int l = d ^ (((d >> 7) & 3) << 4);
    int row = l >> 6, kel = (l & 63) >> 1;
    gA[c] = Az + (long long)(m0 + row) * lda + kel;
    gB[c] = Bz + (long long)(n0 + row) * ldb + kel;
  }

  // fragment read offsets (physical, swizzle folded in; lane-constant XOR)
  const int slotx = (fr >> 1) & 3;
  const int abase = wm * 8192 + fr * 64 + ((fq ^ slotx) << 4);
  const int bbase = 16384 + wn * 4096 + fr * 64 + ((fq ^ slotx) << 4);

  f32x4 acc[8][4];
#pragma unroll
  for (int i = 0; i < 8; ++i)
#pragma unroll
    for (int j = 0; j < 4; ++j) acc[i][j] = (f32x4){0.f, 0.f, 0.f, 0.f};

  const int NT = K >> 5;

  auto stage = [&](int tile) {
    const int k0 = tile << 5;
    char* bufp = lds + (tile & 3) * 32768;
#pragma unroll
    for (int c = 0; c < 2; ++c)
      GL2LDS16(gA[c] + k0, bufp + c * 8192 + wave * 1024);
#pragma unroll
    for (int c = 0; c < 2; ++c)
      GL2LDS16(gB[c] + k0, bufp + 16384 + c * 8192 + wave * 1024);
  };

  stage(0);
  stage(1);
  stage(2);
  WAITV(8);  // tile 0 landed (tiles 1,2 may be outstanding)
  SBAR;

  bf16x8 av[8], bv[4];
  for (int tt = 0; tt < NT - 3; ++tt) {
    const char* bufp = lds + (tt & 3) * 32768;
    stage(tt + 3);  // overwrites buf((tt-1)&3); safe after end-of-(tt-1) bar
#pragma unroll
    for (int i = 0; i < 4; ++i) {
      av[i] = *(const bf16x8*)(bufp + abase + i * 1024);
      av[4 + i] = *(const bf16x8*)(bufp + abase + 4096 + i * 1024);
      bv[i] = *(const bf16x8*)(bufp + bbase + i * 1024);
    }
    WAITL0;  // own ds_reads retired (required before the barrier below)
    __builtin_amdgcn_s_setprio(1);
#pragma unroll
    for (int mi = 0; mi < 8; ++mi)
#pragma unroll
      for (int ni = 0; ni < 4; ++ni)
        acc[mi][ni] = __builtin_amdgcn_mfma_f32_16x16x32_bf16(
            av[mi], bv[ni], acc[mi][ni], 0, 0, 0);
    __builtin_amdgcn_s_setprio(0);
    WAITV(8);  // own loads of tile tt+1 done; barrier makes it global
    SBAR;      // single sync point per K-tile
  }

  // tail: drain all staging, then compute tiles NT-3..NT-1 (no more writers)
  WAITV(0);
  SBAR;
#pragma unroll
  for (int e = 0; e < 3; ++e) {
    const char* bufp = lds + ((NT - 3 + e) & 3) * 32768;
#pragma unroll
    for (int i = 0; i < 4; ++i) {
      av[i] = *(const bf16x8*)(bufp + abase + i * 1024);
      av[4 + i] = *(const bf16x8*)(bufp + abase + 4096 + i * 1024);
      bv[i] = *(const bf16x8*)(bufp + bbase + i * 1024);
    }
#pragma unroll
    for (int mi = 0; mi < 8; ++mi)
#pragma unroll
      for (int ni = 0; ni < 4; ++ni)
        acc[mi][ni] = __builtin_amdgcn_mfma_f32_16x16x32_bf16(
            av[mi], bv[ni], acc[mi][ni], 0, 0, 0);
  }

  // C-write. C/D layout: col = lane&15, row = (lane>>4)*4 + j [m89-verified]
  const float* nrmz = (MODE == 4) ? (norm + z * normOffZ) : nullptr;
  float* Cf = (float*)C + z * cOffZ;
  unsigned short* Cu = (unsigned short*)C + z * cOffZ;
  const bool lower = (m0 < 1024);  // block-uniform (MODE 1: KpT vs VT half)
#pragma unroll
  for (int mi = 0; mi < 8; ++mi) {
    const int rbase = m0 + wm * 128 + mi * 16 + fq * 4;
    float rb[4], nv[4];
#pragma unroll
    for (int j = 0; j < 4; ++j) {
      if (MODE == 1)
        rb[j] = lower ? bias[rbase + j] : bias2[rbase - 1024 + j];
      if (MODE == 4) nv[j] = nrmz[rbase + j];
    }
#pragma unroll
    for (int ni = 0; ni < 4; ++ni) {
      const int c = n0 + wn * 64 + ni * 16 + fr;
      float cb = 0.f;
      if (MODE == 0) cb = bias[c];
#pragma unroll
      for (int j = 0; j < 4; ++j) {
        float v = acc[mi][ni][j];
        if (MODE == 0) v += cb;
        if (MODE == 1) v += rb[j];
        if (MODE == 0 || (MODE == 1 && lower))
          v = (v > 0.f) ? v + 1.f : __expf(v);
        const long long ci = (long long)(rbase + j) * ldc + c;
        if (MODE == 4)
          Cf[ci] = v / nv[j];
        else
          Cu[ci] = f2bf(v);
      }
    }
  }
}

// KVt[b][e][d] = sum_ks P[ks*4+b][e][d]   (P: [16][1024][1024] bf16 partials)
__global__ __launch_bounds__(256) void reduce_kvt(
    const unsigned short* __restrict__ P, unsigned short* __restrict__ KVt) {
  const long long i = ((long long)blockIdx.x * 256 + threadIdx.x) * 8;
  const int b = (int)(i >> 20);
  const long long ed = i & ((1ll << 20) - 1);
  float s[8] = {0.f, 0.f, 0.f, 0.f, 0.f, 0.f, 0.f, 0.f};
#pragma unroll
  for (int ks = 0; ks < 4; ++ks) {
    u16x8 v = *(const u16x8*)(P + ((long long)(ks * 4 + b) << 20) + ed);
#pragma unroll
    for (int j = 0; j < 8; ++j) s[j] += bf2f(v[j]);
  }
  u16x8 o;
#pragma unroll
  for (int j = 0; j < 8; ++j) o[j] = f2bf(s[j]);
  *(u16x8*)(KVt + i) = o;
}

// W [1024(in)][1024(out)] f32  ->  WT [1024(out)][1024(in)] bf16
__global__ __launch_bounds__(256) void transpose_w(
    const float* __restrict__ W, unsigned short* __restrict__ WT) {
  __shared__ float tile[32][33];
  const int tx = threadIdx.x & 31, ty = threadIdx.x >> 5;
  const int i0 = blockIdx.y * 32, o0 = blockIdx.x * 32;
#pragma unroll
  for (int s = 0; s < 32; s += 8)
    tile[ty + s][tx] = W[(long long)(i0 + ty + s) * 1024 + o0 + tx];
  __syncthreads();
#pragma unroll
  for (int s = 0; s < 32; s += 8)
    WT[(long long)(o0 + ty + s) * 1024 + i0 + tx] = f2bf(tile[tx][ty + s]);
}

__global__ __launch_bounds__(256) void convert_x(
    const float4* __restrict__ in, uint2* __restrict__ out, int n4) {
  const int stride = gridDim.x * blockDim.x;
  for (int i = blockIdx.x * blockDim.x + threadIdx.x; i < n4; i += stride) {
    float4 v = in[i];
    uint2 o;
    o.x = (unsigned)f2bf(v.x) | ((unsigned)f2bf(v.y) << 16);
    o.y = (unsigned)f2bf(v.z) | ((unsigned)f2bf(v.w) << 16);
    out[i] = o;
  }
}

// K_sum[b][d] = sum_n KpT[d][b*4096 + n]   (one wave per (b,d), u16x8 loads)
__global__ __launch_bounds__(256) void ksum_kernel(
    const unsigned short* __restrict__ KpT, float* __restrict__ Ksum) {
  const int gw = (blockIdx.x * 256 + threadIdx.x) >> 6;  // 0..4095
  const int lane = threadIdx.x & 63;
  const int d = gw >> 2, b = gw & 3;
  const unsigned short* p = KpT + (long long)d * 16384 + b * 4096 + lane * 8;
  float s = 0.f;
#pragma unroll
  for (int it = 0; it < 8; ++it) {
    u16x8 v = *(const u16x8*)(p + it * 512);
#pragma unroll
    for (int j = 0; j < 8; ++j) s += bf2f(v[j]);
  }
#pragma unroll
  for (int o = 32; o > 0; o >>= 1) s += __shfl_down(s, o, 64);
  if (lane == 0) Ksum[b * 1024 + d] = s;
}

// nrm[m] = eps + sum_d Qp[m][d] * Ksum[b][d]   (one wave per row m)
__global__ __launch_bounds__(256) void norm_kernel(
    const unsigned short* __restrict__ Qp, const float* __restrict__ Ksum,
    float* __restrict__ nrm) {
  const int gw = (blockIdx.x * 256 + threadIdx.x) >> 6;  // 0..16383
  const int lane = threadIdx.x & 63;
  const int b = gw >> 12;
  const unsigned short* q = Qp + (long long)gw * 1024 + lane * 8;
  const float* ks = Ksum + b * 1024 + lane * 8;
  float s = 0.f;
#pragma unroll
  for (int it = 0; it < 2; ++it) {
    u16x8 v = *(const u16x8*)(q + it * 512);
    float4 k0 = *(const float4*)(ks + it * 512);
    float4 k1 = *(const float4*)(ks + it * 512 + 4);
    s += bf2f(v[0]) * k0.x + bf2f(v[1]) * k0.y + bf2f(v[2]) * k0.z +
         bf2f(v[3]) * k0.w + bf2f(v[4]) * k1.x + bf2f(v[5]) * k1.y +
         bf2f(v[6]) * k1.z + bf2f(v[7]) * k1.w;
  }
#pragma unroll
  for (int o = 32; o > 0; o >>= 1) s += __shfl_down(s, o, 64);
  if (lane == 0) nrm[gw] = s + 1e-6f;
}

extern "C" void kernel_launch(void* const* d_in, const int* in_sizes, int n_in,
                              void* d_out, int out_size, void* d_ws,
                              size_t ws_size, hipStream_t stream) {
  const float* x  = (const float*)d_in[0];
  const float* Wq = (const float*)d_in[1];
  const float* bq = (const float*)d_in[2];
  const float* Wk = (const float*)d_in[3];
  const float* bk = (const float*)d_in[4];
  const float* Wv = (const float*)d_in[5];
  const float* bv = (const float*)d_in[6];
  float* out = (float*)d_out;

  const size_t MN = 16384ull * 1024ull;  // B*N*D elements
  char* w = (char*)d_ws;
  unsigned short* xb  = (unsigned short*)w;  w += MN * 2;                 // x bf16; dead after projections -> reused as KVt partials [16][1024][1024]
  unsigned short* WT  = (unsigned short*)w;  w += 3ull * 1024 * 1024 * 2; // Wq^T|Wk^T|Wv^T bf16
  unsigned short* Qp  = (unsigned short*)w;  w += MN * 2;                 // [16384][1024]
  unsigned short* KVb = (unsigned short*)w;  w += 2 * MN * 2;            // [2048][16384]: rows 0-1023 KpT, 1024-2047 VT
  unsigned short* KVt = (unsigned short*)w;  w += 4ull * 1024 * 1024 * 2; // [4][1024(e)][1024(d)]
  float* Ksum = (float*)w;  w += 4ull * 1024 * 4;                         // [4][1024]
  float* nrm  = (float*)w;  w += 16384ull * 4;                            // [16384]
  unsigned short* Pkv = xb;  // split-K KVt partials, aliases dead xb
  unsigned short* KpT = KVb;
  unsigned short* VT  = KVb + MN;

  transpose_w<<<dim3(32, 32), 256, 0, stream>>>(Wq, WT);
  transpose_w<<<dim3(32, 32), 256, 0, stream>>>(Wk, WT + 1024 * 1024);
  transpose_w<<<dim3(32, 32), 256, 0, stream>>>(Wv, WT + 2 * 1024 * 1024);
  convert_x<<<2048, 256, 0, stream>>>((const float4*)x, (uint2*)xb,
                                      (int)(MN / 4));

  // Qp = elu(x @ Wq + bq)+1 : A=xb[16384][1024], Bt=WqT[1024][1024]
  gemm256<0><<<dim3(4, 64, 1), 512, 0, stream>>>(
      xb, 1024, 0, WT, 1024, 0, Qp, 1024, 0, bq, nullptr, nullptr, 0, 1024);
  // merged K/V projection: A=[WkT;WvT][2048][1024], Bt=xb[16384][1024]
  //   rows <1024: KpT = elu(.+bk)+1 ; rows >=1024: VT = . + bv
  gemm256<1><<<dim3(64, 8, 1), 512, 0, stream>>>(
      WT + 1024 * 1024, 1024, 0, xb, 1024, 0, KVb, 16384, 0, bk, bv, nullptr,
      0, 1024);
  ksum_kernel<<<1024, 256, 0, stream>>>(KpT, Ksum);
  // split-K KVt partials: z = ks*4+b; P[z] = VT[:,win] . KpT[:,win]^T
  gemm256<3><<<dim3(4, 4, 16), 512, 0, stream>>>(
      VT, 16384, 0, KpT, 16384, 0, Pkv, 1024, 1024 * 1024, nullptr, nullptr,
      nullptr, 0, 1024);
  reduce_kvt<<<2048, 256, 0, stream>>>(Pkv, KVt);
  norm_kernel<<<4096, 256, 0, stream>>>(Qp, Ksum, nrm);
  // out[b][n][e] = (sum_d Qp[bn][d] * KVt[b][e][d]) / nrm[bn]
  gemm256<4><<<dim3(4, 16, 4), 512, 0, stream>>>(
      Qp, 1024, 4096ll * 1024, KVt, 1024, 1024 * 1024, out, 1024,
      4096ll * 1024, nullptr, nullptr, nrm, 4096, 1024);
}

// Round 6
// 250.946 us; speedup vs baseline: 1.6357x; 1.0153x over previous
//
#include <hip/hip_runtime.h>
#include <hip/hip_bf16.h>
#include <cstdint>

typedef __bf16 bf16x8 __attribute__((ext_vector_type(8)));
typedef float  f32x4  __attribute__((ext_vector_type(4)));
typedef unsigned short u16x8 __attribute__((ext_vector_type(8)));

__device__ __forceinline__ unsigned short f2bf(float f) {
  __hip_bfloat16 h = __float2bfloat16(f);
  return __builtin_bit_cast(unsigned short, h);
}
__device__ __forceinline__ float bf2f(unsigned short u) {
  return __builtin_bit_cast(float, (unsigned)u << 16);
}

#define GL2LDS16(gp, lp)                                                      \
  __builtin_amdgcn_global_load_lds(                                           \
      (const __attribute__((address_space(1))) unsigned int*)(gp),            \
      (__attribute__((address_space(3))) unsigned int*)(lp), 16, 0, 0)

#define SBAR                                                                  \
  {                                                                           \
    __builtin_amdgcn_s_barrier();                                             \
    __builtin_amdgcn_sched_barrier(0);                                        \
  }
#define WAITV(n)                                                              \
  {                                                                           \
    asm volatile("s_waitcnt vmcnt(" #n ")" ::: "memory");                     \
    __builtin_amdgcn_sched_barrier(0);                                        \
  }
#define WAITL0                                                                \
  {                                                                           \
    asm volatile("s_waitcnt lgkmcnt(0)" ::: "memory");                        \
    __builtin_amdgcn_sched_barrier(0);                                        \
  }

// 256x256-tile GEMM, C[m][n] = sum_k A[m][k]*B[n][k] (B transposed layout),
// m201-style phase pipeline. BK=64 per K-tile, 4 phases/tile (= 8 phases per
// 2 K-tiles), 8 waves (2Mx4N), per-wave 128x64 = acc[8][4] 16x16 frags.
// LDS: 2 buffers x 4 sub-tiles {A_k0,B_k0,A_k1,B_k1}, each 256rows x 32k
// (16KB, 64B rows, swizzle phys = l ^ (((l>>7)&3)<<4) on BOTH pre-swizzled
// global source and ds_read address).
// Phase p: {4-8 ds_read; stage 1 sub-tile of t+1; SBAR; lgkm0+schedbar;
//           setprio1; 16 MFMA; setprio0; [vmcnt(4) at P2/P4]; SBAR}
// FIFO wait proof (2 loads/sub-tile): entering t.P1 in-flight=[SA1t,SB1t];
// P1,P2 issue SA0',SB0' -> 8; vmcnt(4)@P2-end retires SA1t,SB1t (P3 reads);
// P3,P4 issue SA1',SB1' -> 8; vmcnt(4)@P4-end retires SA0',SB0' (t+1.P1).
// Never drains below 4. Overwrite-safety: sub-tile staged in t.Px was last
// read in (t-1).Px, lgkm0-retired before that phase's end barrier.
// Modes: 0 Qp (col bias+elu+1, bf16); 1 merged KV-proj (rows<1024:
// bias+elu+1 -> KpT; rows>=1024: bias2 -> VT); 3 split-K KVt partial
// (z=ks*4+b, K-window b*4096+ks*1024); 4 numerator (f32 out, /norm[row]).
template <int MODE>
__global__ __launch_bounds__(512, 2) void gemm256(
    const unsigned short* __restrict__ A, long long lda, long long aOffZ,
    const unsigned short* __restrict__ B, long long ldb, long long bOffZ,
    void* __restrict__ C, long long ldc, long long cOffZ,
    const float* __restrict__ bias, const float* __restrict__ bias2,
    const float* __restrict__ norm, long long normOffZ, int K) {
  __shared__ __attribute__((aligned(16))) char lds[2 * 65536];
  const int t = threadIdx.x;
  const int wave = t >> 6, lane = t & 63;
  const int wm = wave >> 2, wn = wave & 3;
  const int fr = lane & 15, fq = lane >> 4;

  // bijective XCD swizzle on flat xy block id (all grids here are %8==0)
  const int gx = gridDim.x, gy = gridDim.y;
  int flat = blockIdx.y * gx + blockIdx.x;
  const int total = gx * gy;
  if ((total & 7) == 0) flat = (flat & 7) * (total >> 3) + (flat >> 3);
  int bx, by;
  if (MODE == 1) {  // column-major decode: XCD owns few bx across all by
    bx = flat / gy;
    by = flat - bx * gy;
  } else {
    bx = flat % gx;
    by = flat / gx;
  }
  const int m0 = by * 256, n0 = bx * 256;

  const long long z = blockIdx.z;
  long long aBase, bBase;
  if (MODE == 3) {
    const long long koff = (z & 3) * 4096 + (z >> 2) * 1024;
    aBase = koff;
    bBase = koff;
  } else {
    aBase = z * aOffZ;
    bBase = z * bOffZ;
  }
  const unsigned short* Az = A + aBase;
  const unsigned short* Bz = B + bBase;

  // staging: thread t's 16B lands at linear sub-tile byte d = c*8192 + t*16;
  // content there must be logical byte l = d ^ (((d>>7)&3)<<4).
  const unsigned short* gA[2];
  const unsigned short* gB[2];
#pragma unroll
  for (int c = 0; c < 2; ++c) {
    int d = c * 8192 + t * 16;
    int l = d ^ (((d >> 7) & 3) << 4);
    int row = l >> 6, kel = (l & 63) >> 1;
    gA[c] = Az + (long long)(m0 + row) * lda + kel;
    gB[c] = Bz + (long long)(n0 + row) * ldb + kel;
  }

  // fragment read cores (physical, swizzle folded in; lane-constant XOR)
  const int slotx = (fr >> 1) & 3;
  const int acore = wm * 8192 + fr * 64 + ((fq ^ slotx) << 4);
  const int bcore = wn * 4096 + fr * 64 + ((fq ^ slotx) << 4);

  f32x4 acc[8][4];
#pragma unroll
  for (int i = 0; i < 8; ++i)
#pragma unroll
    for (int j = 0; j < 4; ++j) acc[i][j] = (f32x4){0.f, 0.f, 0.f, 0.f};

  const int NT = K >> 6;  // BK=64 K-tiles

  // which: 0=A_k0, 1=B_k0, 2=A_k1, 3=B_k1 (sub-tile base = which*16384)
  auto stage_sub = [&](int tile, int which) {
    char* dst = lds + (tile & 1) * 65536 + which * 16384 + wave * 1024;
    const int kofs = (tile << 6) + ((which >> 1) << 5);
    if (which & 1) {
      GL2LDS16(gB[0] + kofs, dst);
      GL2LDS16(gB[1] + kofs, dst + 8192);
    } else {
      GL2LDS16(gA[0] + kofs, dst);
      GL2LDS16(gA[1] + kofs, dst + 8192);
    }
  };

  // prologue: tile 0's four sub-tiles; A_k0,B_k0 retired before loop
  stage_sub(0, 0);
  stage_sub(0, 1);
  stage_sub(0, 2);
  stage_sub(0, 3);
  WAITV(4);
  SBAR;

  bf16x8 av[4], bv0[4], bv1[4];
  for (int tt = 0; tt < NT - 1; ++tt) {
    const char* bufp = lds + (tt & 1) * 65536;
    // ---- P1: A_k0 mi0-3 + B_k0; stage SA0(t+1)
#pragma unroll
    for (int i = 0; i < 4; ++i) {
      av[i] = *(const bf16x8*)(bufp + acore + i * 1024);
      bv0[i] = *(const bf16x8*)(bufp + 16384 + bcore + i * 1024);
    }
    stage_sub(tt + 1, 0);
    SBAR;
    WAITL0;
    __builtin_amdgcn_s_setprio(1);
#pragma unroll
    for (int mi = 0; mi < 4; ++mi)
#pragma unroll
      for (int ni = 0; ni < 4; ++ni)
        acc[mi][ni] = __builtin_amdgcn_mfma_f32_16x16x32_bf16(
            av[mi], bv0[ni], acc[mi][ni], 0, 0, 0);
    __builtin_amdgcn_s_setprio(0);
    SBAR;
    // ---- P2: A_k0 mi4-7 (reuse B_k0); stage SB0(t+1)
#pragma unroll
    for (int i = 0; i < 4; ++i)
      av[i] = *(const bf16x8*)(bufp + acore + (4 + i) * 1024);
    stage_sub(tt + 1, 1);
    SBAR;
    WAITL0;
    __builtin_amdgcn_s_setprio(1);
#pragma unroll
    for (int mi = 0; mi < 4; ++mi)
#pragma unroll
      for (int ni = 0; ni < 4; ++ni)
        acc[4 + mi][ni] = __builtin_amdgcn_mfma_f32_16x16x32_bf16(
            av[mi], bv0[ni], acc[4 + mi][ni], 0, 0, 0);
    __builtin_amdgcn_s_setprio(0);
    WAITV(4);  // retire SA1(t),SB1(t) -> P3 may read them
    SBAR;
    // ---- P3: A_k1 mi0-3 + B_k1; stage SA1(t+1)
#pragma unroll
    for (int i = 0; i < 4; ++i) {
      av[i] = *(const bf16x8*)(bufp + 32768 + acore + i * 1024);
      bv1[i] = *(const bf16x8*)(bufp + 49152 + bcore + i * 1024);
    }
    stage_sub(tt + 1, 2);
    SBAR;
    WAITL0;
    __builtin_amdgcn_s_setprio(1);
#pragma unroll
    for (int mi = 0; mi < 4; ++mi)
#pragma unroll
      for (int ni = 0; ni < 4; ++ni)
        acc[mi][ni] = __builtin_amdgcn_mfma_f32_16x16x32_bf16(
            av[mi], bv1[ni], acc[mi][ni], 0, 0, 0);
    __builtin_amdgcn_s_setprio(0);
    SBAR;
    // ---- P4: A_k1 mi4-7 (reuse B_k1); stage SB1(t+1)
#pragma unroll
    for (int i = 0; i < 4; ++i)
      av[i] = *(const bf16x8*)(bufp + 32768 + acore + (4 + i) * 1024);
    stage_sub(tt + 1, 3);
    SBAR;
    WAITL0;
    __builtin_amdgcn_s_setprio(1);
#pragma unroll
    for (int mi = 0; mi < 4; ++mi)
#pragma unroll
      for (int ni = 0; ni < 4; ++ni)
        acc[4 + mi][ni] = __builtin_amdgcn_mfma_f32_16x16x32_bf16(
            av[mi], bv1[ni], acc[4 + mi][ni], 0, 0, 0);
    __builtin_amdgcn_s_setprio(0);
    WAITV(4);  // retire SA0(t+1),SB0(t+1) -> next P1 may read them
    SBAR;
  }

  // ---- last tile (NT-1): same 4 phases, no staging; drain at P2-end
  {
    const char* bufp = lds + ((NT - 1) & 1) * 65536;
#pragma unroll
    for (int i = 0; i < 4; ++i) {
      av[i] = *(const bf16x8*)(bufp + acore + i * 1024);
      bv0[i] = *(const bf16x8*)(bufp + 16384 + bcore + i * 1024);
    }
    SBAR;
    WAITL0;
#pragma unroll
    for (int mi = 0; mi < 4; ++mi)
#pragma unroll
      for (int ni = 0; ni < 4; ++ni)
        acc[mi][ni] = __builtin_amdgcn_mfma_f32_16x16x32_bf16(
            av[mi], bv0[ni], acc[mi][ni], 0, 0, 0);
    SBAR;
#pragma unroll
    for (int i = 0; i < 4; ++i)
      av[i] = *(const bf16x8*)(bufp + acore + (4 + i) * 1024);
    SBAR;
    WAITL0;
#pragma unroll
    for (int mi = 0; mi < 4; ++mi)
#pragma unroll
      for (int ni = 0; ni < 4; ++ni)
        acc[4 + mi][ni] = __builtin_amdgcn_mfma_f32_16x16x32_bf16(
            av[mi], bv0[ni], acc[4 + mi][ni], 0, 0, 0);
    WAITV(0);  // retire SA1,SB1 of last tile
    SBAR;
#pragma unroll
    for (int i = 0; i < 4; ++i) {
      av[i] = *(const bf16x8*)(bufp + 32768 + acore + i * 1024);
      bv1[i] = *(const bf16x8*)(bufp + 49152 + bcore + i * 1024);
    }
    WAITL0;
#pragma unroll
    for (int mi = 0; mi < 4; ++mi)
#pragma unroll
      for (int ni = 0; ni < 4; ++ni)
        acc[mi][ni] = __builtin_amdgcn_mfma_f32_16x16x32_bf16(
            av[mi], bv1[ni], acc[mi][ni], 0, 0, 0);
#pragma unroll
    for (int i = 0; i < 4; ++i)
      av[i] = *(const bf16x8*)(bufp + 32768 + acore + (4 + i) * 1024);
    WAITL0;
#pragma unroll
    for (int mi = 0; mi < 4; ++mi)
#pragma unroll
      for (int ni = 0; ni < 4; ++ni)
        acc[4 + mi][ni] = __builtin_amdgcn_mfma_f32_16x16x32_bf16(
            av[mi], bv1[ni], acc[4 + mi][ni], 0, 0, 0);
  }

  // C-write. C/D layout: col = lane&15, row = (lane>>4)*4 + j [m89-verified]
  const float* nrmz = (MODE == 4) ? (norm + z * normOffZ) : nullptr;
  float* Cf = (float*)C + z * cOffZ;
  unsigned short* Cu = (unsigned short*)C + z * cOffZ;
  const bool lower = (m0 < 1024);  // block-uniform (MODE 1: KpT vs VT half)
#pragma unroll
  for (int mi = 0; mi < 8; ++mi) {
    const int rbase = m0 + wm * 128 + mi * 16 + fq * 4;
    float rb[4], nv[4];
#pragma unroll
    for (int j = 0; j < 4; ++j) {
      if (MODE == 1)
        rb[j] = lower ? bias[rbase + j] : bias2[rbase - 1024 + j];
      if (MODE == 4) nv[j] = nrmz[rbase + j];
    }
#pragma unroll
    for (int ni = 0; ni < 4; ++ni) {
      const int c = n0 + wn * 64 + ni * 16 + fr;
      float cb = 0.f;
      if (MODE == 0) cb = bias[c];
#pragma unroll
      for (int j = 0; j < 4; ++j) {
        float v = acc[mi][ni][j];
        if (MODE == 0) v += cb;
        if (MODE == 1) v += rb[j];
        if (MODE == 0 || (MODE == 1 && lower))
          v = (v > 0.f) ? v + 1.f : __expf(v);
        const long long ci = (long long)(rbase + j) * ldc + c;
        if (MODE == 4)
          Cf[ci] = v / nv[j];
        else
          Cu[ci] = f2bf(v);
      }
    }
  }
}

// KVt[b][e][d] = sum_ks P[ks*4+b][e][d]   (P: [16][1024][1024] bf16 partials)
__global__ __launch_bounds__(256) void reduce_kvt(
    const unsigned short* __restrict__ P, unsigned short* __restrict__ KVt) {
  const long long i = ((long long)blockIdx.x * 256 + threadIdx.x) * 8;
  const int b = (int)(i >> 20);
  const long long ed = i & ((1ll << 20) - 1);
  float s[8] = {0.f, 0.f, 0.f, 0.f, 0.f, 0.f, 0.f, 0.f};
#pragma unroll
  for (int ks = 0; ks < 4; ++ks) {
    u16x8 v = *(const u16x8*)(P + ((long long)(ks * 4 + b) << 20) + ed);
#pragma unroll
    for (int j = 0; j < 8; ++j) s[j] += bf2f(v[j]);
  }
  u16x8 o;
#pragma unroll
  for (int j = 0; j < 8; ++j) o[j] = f2bf(s[j]);
  *(u16x8*)(KVt + i) = o;
}

// W [1024(in)][1024(out)] f32  ->  WT [1024(out)][1024(in)] bf16
__global__ __launch_bounds__(256) void transpose_w(
    const float* __restrict__ W, unsigned short* __restrict__ WT) {
  __shared__ float tile[32][33];
  const int tx = threadIdx.x & 31, ty = threadIdx.x >> 5;
  const int i0 = blockIdx.y * 32, o0 = blockIdx.x * 32;
#pragma unroll
  for (int s = 0; s < 32; s += 8)
    tile[ty + s][tx] = W[(long long)(i0 + ty + s) * 1024 + o0 + tx];
  __syncthreads();
#pragma unroll
  for (int s = 0; s < 32; s += 8)
    WT[(long long)(o0 + ty + s) * 1024 + i0 + tx] = f2bf(tile[tx][ty + s]);
}

__global__ __launch_bounds__(256) void convert_x(
    const float4* __restrict__ in, uint2* __restrict__ out, int n4) {
  const int stride = gridDim.x * blockDim.x;
  for (int i = blockIdx.x * blockDim.x + threadIdx.x; i < n4; i += stride) {
    float4 v = in[i];
    uint2 o;
    o.x = (unsigned)f2bf(v.x) | ((unsigned)f2bf(v.y) << 16);
    o.y = (unsigned)f2bf(v.z) | ((unsigned)f2bf(v.w) << 16);
    out[i] = o;
  }
}

// K_sum[b][d] = sum_n KpT[d][b*4096 + n]   (one wave per (b,d), u16x8 loads)
__global__ __launch_bounds__(256) void ksum_kernel(
    const unsigned short* __restrict__ KpT, float* __restrict__ Ksum) {
  const int gw = (blockIdx.x * 256 + threadIdx.x) >> 6;  // 0..4095
  const int lane = threadIdx.x & 63;
  const int d = gw >> 2, b = gw & 3;
  const unsigned short* p = KpT + (long long)d * 16384 + b * 4096 + lane * 8;
  float s = 0.f;
#pragma unroll
  for (int it = 0; it < 8; ++it) {
    u16x8 v = *(const u16x8*)(p + it * 512);
#pragma unroll
    for (int j = 0; j < 8; ++j) s += bf2f(v[j]);
  }
#pragma unroll
  for (int o = 32; o > 0; o >>= 1) s += __shfl_down(s, o, 64);
  if (lane == 0) Ksum[b * 1024 + d] = s;
}

// nrm[m] = eps + sum_d Qp[m][d] * Ksum[b][d]   (one wave per row m)
__global__ __launch_bounds__(256) void norm_kernel(
    const unsigned short* __restrict__ Qp, const float* __restrict__ Ksum,
    float* __restrict__ nrm) {
  const int gw = (blockIdx.x * 256 + threadIdx.x) >> 6;  // 0..16383
  const int lane = threadIdx.x & 63;
  const int b = gw >> 12;
  const unsigned short* q = Qp + (long long)gw * 1024 + lane * 8;
  const float* ks = Ksum + b * 1024 + lane * 8;
  float s = 0.f;
#pragma unroll
  for (int it = 0; it < 2; ++it) {
    u16x8 v = *(const u16x8*)(q + it * 512);
    float4 k0 = *(const float4*)(ks + it * 512);
    float4 k1 = *(const float4*)(ks + it * 512 + 4);
    s += bf2f(v[0]) * k0.x + bf2f(v[1]) * k0.y + bf2f(v[2]) * k0.z +
         bf2f(v[3]) * k0.w + bf2f(v[4]) * k1.x + bf2f(v[5]) * k1.y +
         bf2f(v[6]) * k1.z + bf2f(v[7]) * k1.w;
  }
#pragma unroll
  for (int o = 32; o > 0; o >>= 1) s += __shfl_down(s, o, 64);
  if (lane == 0) nrm[gw] = s + 1e-6f;
}

extern "C" void kernel_launch(void* const* d_in, const int* in_sizes, int n_in,
                              void* d_out, int out_size, void* d_ws,
                              size_t ws_size, hipStream_t stream) {
  const float* x  = (const float*)d_in[0];
  const float* Wq = (const float*)d_in[1];
  const float* bq = (const float*)d_in[2];
  const float* Wk = (const float*)d_in[3];
  const float* bk = (const float*)d_in[4];
  const float* Wv = (const float*)d_in[5];
  const float* bv = (const float*)d_in[6];
  float* out = (float*)d_out;

  const size_t MN = 16384ull * 1024ull;  // B*N*D elements
  char* w = (char*)d_ws;
  unsigned short* xb  = (unsigned short*)w;  w += MN * 2;                 // x bf16; dead after projections -> reused as KVt partials [16][1024][1024]
  unsigned short* WT  = (unsigned short*)w;  w += 3ull * 1024 * 1024 * 2; // Wq^T|Wk^T|Wv^T bf16
  unsigned short* Qp  = (unsigned short*)w;  w += MN * 2;                 // [16384][1024]
  unsigned short* KVb = (unsigned short*)w;  w += 2 * MN * 2;            // [2048][16384]: rows 0-1023 KpT, 1024-2047 VT
  unsigned short* KVt = (unsigned short*)w;  w += 4ull * 1024 * 1024 * 2; // [4][1024(e)][1024(d)]
  float* Ksum = (float*)w;  w += 4ull * 1024 * 4;                         // [4][1024]
  float* nrm  = (float*)w;  w += 16384ull * 4;                            // [16384]
  unsigned short* Pkv = xb;  // split-K KVt partials, aliases dead xb
  unsigned short* KpT = KVb;
  unsigned short* VT  = KVb + MN;

  transpose_w<<<dim3(32, 32), 256, 0, stream>>>(Wq, WT);
  transpose_w<<<dim3(32, 32), 256, 0, stream>>>(Wk, WT + 1024 * 1024);
  transpose_w<<<dim3(32, 32), 256, 0, stream>>>(Wv, WT + 2 * 1024 * 1024);
  convert_x<<<2048, 256, 0, stream>>>((const float4*)x, (uint2*)xb,
                                      (int)(MN / 4));

  // Qp = elu(x @ Wq + bq)+1 : A=xb[16384][1024], Bt=WqT[1024][1024]
  gemm256<0><<<dim3(4, 64, 1), 512, 0, stream>>>(
      xb, 1024, 0, WT, 1024, 0, Qp, 1024, 0, bq, nullptr, nullptr, 0, 1024);
  // merged K/V projection: A=[WkT;WvT][2048][1024], Bt=xb[16384][1024]
  //   rows <1024: KpT = elu(.+bk)+1 ; rows >=1024: VT = . + bv
  gemm256<1><<<dim3(64, 8, 1), 512, 0, stream>>>(
      WT + 1024 * 1024, 1024, 0, xb, 1024, 0, KVb, 16384, 0, bk, bv, nullptr,
      0, 1024);
  ksum_kernel<<<1024, 256, 0, stream>>>(KpT, Ksum);
  // split-K KVt partials: z = ks*4+b; P[z] = VT[:,win] . KpT[:,win]^T
  gemm256<3><<<dim3(4, 4, 16), 512, 0, stream>>>(
      VT, 16384, 0, KpT, 16384, 0, Pkv, 1024, 1024 * 1024, nullptr, nullptr,
      nullptr, 0, 1024);
  reduce_kvt<<<2048, 256, 0, stream>>>(Pkv, KVt);
  norm_kernel<<<4096, 256, 0, stream>>>(Qp, Ksum, nrm);
  // out[b][n][e] = (sum_d Qp[bn][d] * KVt[b][e][d]) / nrm[bn]
  gemm256<4><<<dim3(4, 16, 4), 512, 0, stream>>>(
      Qp, 1024, 4096ll * 1024, KVt, 1024, 1024 * 1024, out, 1024,
      4096ll * 1024, nullptr, nullptr, nrm, 4096, 1024);
}